// Round 1
// baseline (2118.319 us; speedup 1.0000x reference)
//
#include <hip/hip_runtime.h>
#include <math.h>

#define NTOK 2304
#define CDIM 768
#define NH 12
#define HD 64
#define HGRID 48

__device__ __forceinline__ float wave_sum(float v){
  #pragma unroll
  for (int o = 32; o > 0; o >>= 1) v += __shfl_xor(v, o);
  return v;
}
__device__ __forceinline__ float wave_max(float v){
  #pragma unroll
  for (int o = 32; o > 0; o >>= 1) v = fmaxf(v, __shfl_xor(v, o));
  return v;
}

// ---------------- LayerNorm: one block per row, C=768 ----------------
__global__ __launch_bounds__(256) void ln_kernel(const float* __restrict__ x,
    const float* __restrict__ g, const float* __restrict__ b,
    float* __restrict__ out){
  __shared__ float sm[4];
  const int row = blockIdx.x;
  const int tid = threadIdx.x;
  const float* xr = x + (size_t)row * CDIM;
  float v0 = xr[tid], v1 = xr[tid + 256], v2 = xr[tid + 512];
  float s = wave_sum(v0 + v1 + v2);
  if ((tid & 63) == 0) sm[tid >> 6] = s;
  __syncthreads();
  float mean = (sm[0] + sm[1] + sm[2] + sm[3]) * (1.0f / CDIM);
  __syncthreads();
  float d0 = v0 - mean, d1 = v1 - mean, d2 = v2 - mean;
  float ss = wave_sum(d0 * d0 + d1 * d1 + d2 * d2);
  if ((tid & 63) == 0) sm[tid >> 6] = ss;
  __syncthreads();
  float var = (sm[0] + sm[1] + sm[2] + sm[3]) * (1.0f / CDIM);
  float rstd = rsqrtf(var + 1e-6f);
  float* outr = out + (size_t)row * CDIM;
  outr[tid]       = d0 * rstd * g[tid]       + b[tid];
  outr[tid + 256] = d1 * rstd * g[tid + 256] + b[tid + 256];
  outr[tid + 512] = d2 * rstd * g[tid + 512] + b[tid + 512];
}

// ---------------- fp32 GEMM: C[M,N] = A[M,K]@B[K,N] + bias (+gelu)(+res) ----
// 128x128 tile, BK=8, 256 threads, 8x8 per thread. All dims divide evenly.
template<int ACT, int RES>
__global__ __launch_bounds__(256) void gemm_kernel(
    const float* __restrict__ A, const float* __restrict__ B,
    const float* __restrict__ bias, const float* __restrict__ res,
    float* __restrict__ C, int M, int K, int N){
  __shared__ float As[8][132];   // stored transposed: As[k][m]
  __shared__ float Bs[8][132];
  const int tid = threadIdx.x;
  const int bm = blockIdx.y * 128, bn = blockIdx.x * 128;
  const int tx = tid & 15, ty = tid >> 4;
  float acc[8][8];
  #pragma unroll
  for (int i = 0; i < 8; ++i)
    #pragma unroll
    for (int j = 0; j < 8; ++j) acc[i][j] = 0.f;

  const int ar = (tid * 4) >> 3, ac = (tid * 4) & 7;     // A: 128 rows x 8 k
  const int br = (tid * 4) >> 7, bc = (tid * 4) & 127;   // B: 8 k x 128 cols
  const float* Aptr = A + (size_t)(bm + ar) * K + ac;
  const float* Bptr = B + (size_t)br * N + bn + bc;

  for (int k0 = 0; k0 < K; k0 += 8){
    float4 av = *(const float4*)(Aptr + k0);
    float4 bv = *(const float4*)(Bptr + (size_t)k0 * N);
    As[ac + 0][ar] = av.x; As[ac + 1][ar] = av.y;
    As[ac + 2][ar] = av.z; As[ac + 3][ar] = av.w;
    *(float4*)&Bs[br][bc] = bv;
    __syncthreads();
    #pragma unroll
    for (int kk = 0; kk < 8; ++kk){
      float a[8], bb[8];
      #pragma unroll
      for (int i = 0; i < 8; ++i) a[i] = As[kk][ty * 8 + i];
      #pragma unroll
      for (int j = 0; j < 8; ++j) bb[j] = Bs[kk][tx * 8 + j];
      #pragma unroll
      for (int i = 0; i < 8; ++i)
        #pragma unroll
        for (int j = 0; j < 8; ++j) acc[i][j] = fmaf(a[i], bb[j], acc[i][j]);
    }
    __syncthreads();
  }
  #pragma unroll
  for (int i = 0; i < 8; ++i){
    const int row = bm + ty * 8 + i;
    #pragma unroll
    for (int j = 0; j < 8; ++j){
      const int col = bn + tx * 8 + j;
      float v = acc[i][j] + bias[col];
      if (ACT == 1) v = 0.5f * v * (1.0f + erff(v * 0.70710678118654752f));
      if (RES) v += res[(size_t)row * N + col];
      C[(size_t)row * N + col] = v;
    }
  }
}

// ---------------- flash attention with decomposed rel-pos --------------------
// grid: (NTOK/4, NH). block: 256 threads = 4 waves, one query per wave.
// qkv layout per token row: [q(768) | k(768) | v(768)], head offset h*64.
// out written in (N, C) layout: out[n*768 + head*64 + d].
__global__ __launch_bounds__(256) void attn_kernel(
    const float* __restrict__ qkv, const float* __restrict__ rph,
    const float* __restrict__ rpw, float* __restrict__ out){
  __shared__ float k_lds[64][65];
  __shared__ float v_lds[64][65];
  __shared__ float q_lds[4][64];
  __shared__ float p_lds[4][64];
  __shared__ float rlh[4][48];
  __shared__ float rlw[4][48];

  const int tid = threadIdx.x;
  const int w = tid >> 6, lane = tid & 63;
  const int head = blockIdx.y;
  const int n = blockIdx.x * 4 + w;          // query token
  const int hq = n / HGRID, wq = n - hq * HGRID;

  q_lds[w][lane] = qkv[(size_t)n * (3 * CDIM) + head * HD + lane];
  __syncthreads();

  // per-query rel-pos dot tables: rlh[w][hk] = q . rel_pos_h[hq-hk+47]
  if (lane < HGRID){
    const float* rh = rph + (size_t)(hq - lane + 47) * HD;
    const float* rw = rpw + (size_t)(wq - lane + 47) * HD;
    float sh = 0.f, sw = 0.f;
    for (int d = 0; d < HD; ++d){
      float qd = q_lds[w][d];
      sh = fmaf(qd, rh[d], sh);
      sw = fmaf(qd, rw[d], sw);
    }
    rlh[w][lane] = sh; rlw[w][lane] = sw;
  }
  __syncthreads();

  const float scale = 0.125f;   // 64^-0.5
  float m_run = -3.0e38f, l_run = 0.f, acc = 0.f;
  const float* kbase = qkv + CDIM + head * HD;
  const float* vbase = qkv + 2 * CDIM + head * HD;

  for (int c = 0; c < NTOK / 64; ++c){
    __syncthreads();
    #pragma unroll
    for (int i = 0; i < 16; ++i){          // stage 64 keys x 64 dims (K and V)
      int e = tid + i * 256;
      int key = e >> 6, d = e & 63;
      size_t g = (size_t)(c * 64 + key) * (3 * CDIM) + d;
      k_lds[key][d] = kbase[g];
      v_lds[key][d] = vbase[g];
    }
    __syncthreads();

    const int m = c * 64 + lane;
    const int hk = m / HGRID, wk = m - hk * HGRID;
    float s = 0.f;
    #pragma unroll
    for (int d = 0; d < HD; ++d) s = fmaf(q_lds[w][d], k_lds[lane][d], s);
    s = s * scale + rlh[w][hk] + rlw[w][wk];

    float cmax = wave_max(s);
    float nm = fmaxf(m_run, cmax);
    float f = __expf(m_run - nm);
    float p = __expf(s - nm);
    l_run = l_run * f + wave_sum(p);
    p_lds[w][lane] = p;
    acc *= f;
    #pragma unroll
    for (int mm = 0; mm < 64; ++mm)
      acc = fmaf(p_lds[w][mm], v_lds[mm][lane], acc);
    m_run = nm;
  }
  out[(size_t)n * CDIM + head * HD + lane] = acc / l_run;
}

extern "C" void kernel_launch(void* const* d_in, const int* in_sizes, int n_in,
                              void* d_out, int out_size, void* d_ws, size_t ws_size,
                              hipStream_t stream) {
  const float* x      = (const float*)d_in[0];
  const float* ln1_g  = (const float*)d_in[1];
  const float* ln1_b  = (const float*)d_in[2];
  const float* qkv_w  = (const float*)d_in[3];
  const float* qkv_b  = (const float*)d_in[4];
  const float* rph    = (const float*)d_in[5];
  const float* rpw    = (const float*)d_in[6];
  const float* proj_w = (const float*)d_in[7];
  const float* proj_b = (const float*)d_in[8];
  const float* ln2_g  = (const float*)d_in[9];
  const float* ln2_b  = (const float*)d_in[10];
  const float* mlp_w1 = (const float*)d_in[11];
  const float* mlp_b1 = (const float*)d_in[12];
  const float* mlp_w2 = (const float*)d_in[13];
  const float* mlp_b2 = (const float*)d_in[14];
  float* out = (float*)d_out;
  float* ws  = (float*)d_ws;

  // workspace layout (floats): xn/y | qkv-or-h | attnout | x1
  float* xn  = ws;                       // 1,769,472
  float* big = ws + 1769472;             // 7,077,888 (qkv, later mlp hidden)
  float* att = ws + 8847360;             // 1,769,472
  float* x1  = ws + 10616832;            // 1,769,472  (total 49.5 MB)

  // 1) xn = LN1(x)
  ln_kernel<<<NTOK, 256, 0, stream>>>(x, ln1_g, ln1_b, xn);
  // 2) qkv = xn @ qkv_w + qkv_b            (2304 x 768 x 2304)
  gemm_kernel<0,0><<<dim3(2304/128, 2304/128), 256, 0, stream>>>(
      xn, qkv_w, qkv_b, nullptr, big, NTOK, CDIM, 3*CDIM);
  // 3) att = attention(qkv, relpos)        -> (N, C) layout
  attn_kernel<<<dim3(NTOK/4, NH), 256, 0, stream>>>(big, rph, rpw, att);
  // 4) x1 = x + att @ proj_w + proj_b      (2304 x 768 x 768)
  gemm_kernel<0,1><<<dim3(768/128, 2304/128), 256, 0, stream>>>(
      att, proj_w, proj_b, x, x1, NTOK, CDIM, CDIM);
  // 5) y = LN2(x1)  (reuse xn)
  ln_kernel<<<NTOK, 256, 0, stream>>>(x1, ln2_g, ln2_b, xn);
  // 6) h = gelu(y @ mlp_w1 + mlp_b1)       (2304 x 768 x 3072)
  gemm_kernel<1,0><<<dim3(3072/128, 2304/128), 256, 0, stream>>>(
      xn, mlp_w1, mlp_b1, nullptr, big, NTOK, CDIM, 4*CDIM);
  // 7) out = x1 + h @ mlp_w2 + mlp_b2      (2304 x 3072 x 768)
  gemm_kernel<0,1><<<dim3(768/128, 2304/128), 256, 0, stream>>>(
      big, mlp_w2, mlp_b2, x1, out, NTOK, 4*CDIM, CDIM);
}

// Round 2
// 339.542 us; speedup vs baseline: 6.2387x; 6.2387x over previous
//
#include <hip/hip_runtime.h>
#include <hip/hip_bf16.h>
#include <math.h>

#define NTOK 2304
#define CDIM 768

typedef __attribute__((ext_vector_type(8))) short bf16x8;
typedef __attribute__((ext_vector_type(4))) float f32x4;

#define MFMA16(a,b,c) __builtin_amdgcn_mfma_f32_16x16x32_bf16(a,b,c,0,0,0)
#define GLOAD16(g, l) __builtin_amdgcn_global_load_lds( \
    (const __attribute__((address_space(1))) void*)(g), \
    (__attribute__((address_space(3))) void*)(l), 16, 0, 0)

__device__ __forceinline__ short f2b(float f){
  __hip_bfloat16 h = __float2bfloat16(f);
  short s; __builtin_memcpy(&s, &h, 2); return s;
}
__device__ __forceinline__ float b2f(short s){
  __hip_bfloat16 h; __builtin_memcpy(&h, &s, 2); return __bfloat162float(h);
}
__device__ __forceinline__ unsigned cvtpk(float a, float b){
  unsigned r;
  asm("v_cvt_pk_bf16_f32 %0, %1, %2" : "=v"(r) : "v"(a), "v"(b));
  return r;
}
__device__ __forceinline__ float wsum(float v){
  #pragma unroll
  for (int o = 32; o > 0; o >>= 1) v += __shfl_xor(v, o);
  return v;
}

// ---------------- LayerNorm (f32 in, bf16 out) ----------------
__global__ __launch_bounds__(256) void ln_kernel(const float* __restrict__ x,
    const float* __restrict__ g, const float* __restrict__ b,
    __hip_bfloat16* __restrict__ out){
  __shared__ float sm[4];
  const int row = blockIdx.x, tid = threadIdx.x;
  const float* xr = x + (size_t)row * CDIM;
  float v0 = xr[tid], v1 = xr[tid+256], v2 = xr[tid+512];
  float s = wsum(v0+v1+v2);
  if ((tid & 63)==0) sm[tid>>6] = s;
  __syncthreads();
  float mean = (sm[0]+sm[1]+sm[2]+sm[3]) * (1.0f/CDIM);
  __syncthreads();
  float d0=v0-mean, d1=v1-mean, d2=v2-mean;
  float ss = wsum(d0*d0+d1*d1+d2*d2);
  if ((tid&63)==0) sm[tid>>6] = ss;
  __syncthreads();
  float rstd = rsqrtf((sm[0]+sm[1]+sm[2]+sm[3])*(1.0f/CDIM) + 1e-6f);
  __hip_bfloat16* o = out + (size_t)row*CDIM;
  o[tid]     = __float2bfloat16(d0*rstd*g[tid]     + b[tid]);
  o[tid+256] = __float2bfloat16(d1*rstd*g[tid+256] + b[tid+256]);
  o[tid+512] = __float2bfloat16(d2*rstd*g[tid+512] + b[tid+512]);
}

// ------------- weight transpose+cast: W f32[K][N] -> Wt bf16[N][K] -------------
__global__ __launch_bounds__(256) void wt_kernel(const float* __restrict__ W,
    __hip_bfloat16* __restrict__ Wt, int K, int N){
  __shared__ float t[32][33];
  const int n0 = blockIdx.x*32, k0 = blockIdx.y*32;
  const int c = threadIdx.x & 31, r0 = threadIdx.x >> 5;
  #pragma unroll
  for (int i = 0; i < 4; ++i){
    int r = r0 + i*8;
    t[r][c] = W[(size_t)(k0 + r)*N + n0 + c];
  }
  __syncthreads();
  #pragma unroll
  for (int i = 0; i < 4; ++i){
    int r = r0 + i*8;
    Wt[(size_t)(n0 + r)*K + k0 + c] = __float2bfloat16(t[c][r]);
  }
}

// ------------- rel-pos cast f32 -> bf16 (both tables) -------------
__global__ __launch_bounds__(256) void castrp(const float* __restrict__ rph,
    const float* __restrict__ rpw, __hip_bfloat16* __restrict__ rphb,
    __hip_bfloat16* __restrict__ rpwb){
  int i = blockIdx.x*256 + threadIdx.x;
  if (i < 95*64){ rphb[i] = __float2bfloat16(rph[i]); rpwb[i] = __float2bfloat16(rpw[i]); }
}

// ------------- V transpose: qkvb[n][1536+h*64+d] -> Vtg[h][d][n] -------------
__global__ __launch_bounds__(256) void vt_kernel(const __hip_bfloat16* __restrict__ qkvb,
    __hip_bfloat16* __restrict__ Vtg){
  __shared__ __hip_bfloat16 t[32][33];
  const int n0 = blockIdx.x*32, d0 = blockIdx.y*32, h = blockIdx.z;
  const int c = threadIdx.x & 31, r0 = threadIdx.x >> 5;
  #pragma unroll
  for (int i = 0; i < 4; ++i){
    int r = r0 + i*8;
    t[r][c] = qkvb[(size_t)(n0+r)*NTOK + 1536 + h*64 + d0 + c];
  }
  __syncthreads();
  #pragma unroll
  for (int i = 0; i < 4; ++i){
    int r = r0 + i*8;
    Vtg[((size_t)h*64 + d0 + r)*NTOK + n0 + c] = t[c][r];
  }
}

// ------------- bf16 MFMA GEMM: C[M][N] = A[M][K] @ Bt[N][K]^T + bias -------------
template<int ACT, int RES, int OBF>
__global__ __launch_bounds__(256) void gemm_bf16(
    const __hip_bfloat16* __restrict__ A, const __hip_bfloat16* __restrict__ Bt,
    const float* __restrict__ bias, const float* __restrict__ res,
    void* __restrict__ Cout, int M, int K, int N){
  __shared__ short As[128*32];
  __shared__ short Bs[128*32];
  const int tid = threadIdx.x;
  const int w = tid >> 6, lane = tid & 63;
  const int wr = w >> 1, wc = w & 1;
  const int bm = blockIdx.y*128, bn = blockIdx.x*128;
  const int l15 = lane & 15, l4 = lane >> 4;
  f32x4 acc[4][4] = {};

  const int ra = wr*64 + l15;
  const int rb = wc*64 + l15;
  const int kswa = l4 ^ ((ra>>1)&3);
  const int kswb = l4 ^ ((rb>>1)&3);

  for (int k0 = 0; k0 < K; k0 += 32){
    __syncthreads();
    #pragma unroll
    for (int i = 0; i < 2; ++i){
      int e = i*256 + tid;
      int row = e >> 2, s = e & 3;
      int gs = s ^ ((row>>1)&3);
      int e0 = i*256 + w*64;
      GLOAD16(A  + (size_t)(bm+row)*K + k0 + gs*8, (char*)As + e0*16);
      GLOAD16(Bt + (size_t)(bn+row)*K + k0 + gs*8, (char*)Bs + e0*16);
    }
    __syncthreads();
    bf16x8 af[4], bfr[4];
    #pragma unroll
    for (int m = 0; m < 4; ++m)
      af[m] = *(const bf16x8*)((const char*)As + (ra + m*16)*64 + kswa*16);
    #pragma unroll
    for (int n = 0; n < 4; ++n)
      bfr[n] = *(const bf16x8*)((const char*)Bs + (rb + n*16)*64 + kswb*16);
    #pragma unroll
    for (int m = 0; m < 4; ++m)
      #pragma unroll
      for (int n = 0; n < 4; ++n)
        acc[m][n] = MFMA16(af[m], bfr[n], acc[m][n]);
  }

  const int crow = bm + wr*64 + l4*4;
  const int ccol = bn + wc*64 + l15;
  #pragma unroll
  for (int m = 0; m < 4; ++m){
    #pragma unroll
    for (int n = 0; n < 4; ++n){
      #pragma unroll
      for (int r = 0; r < 4; ++r){
        int rr = crow + m*16 + r, cc = ccol + n*16;
        float v = acc[m][n][r] + bias[cc];
        if (ACT == 1) v = 0.5f * v * (1.0f + erff(v * 0.70710678118654752f));
        if (RES) v += res[(size_t)rr*N + cc];
        if (OBF) ((__hip_bfloat16*)Cout)[(size_t)rr*N + cc] = __float2bfloat16(v);
        else     ((float*)Cout)[(size_t)rr*N + cc] = v;
      }
    }
  }
}

// ------------- MFMA flash attention with decomposed rel-pos -------------
// grid (36, 12): 64 queries/block (4 waves x 16q), chunks of 64 keys.
__global__ __launch_bounds__(256) void attn_mfma(
    const __hip_bfloat16* __restrict__ qkvb,  // [2304][2304]
    const __hip_bfloat16* __restrict__ Vtg,   // [12][64][2304]
    const __hip_bfloat16* __restrict__ rphb,  // [95][64]
    const __hip_bfloat16* __restrict__ rpwb,  // [95][64]
    __hip_bfloat16* __restrict__ attb){       // [2304][768]
  __shared__ short Ks[64*64];        // [key][d], 16B slot s stores global slot s^(key&7)
  __shared__ short Vs[64*64];        // [d][key], slot s stores global key-slot s^(d&7)
  __shared__ float rlh[4][16][50];
  __shared__ float rlt[4][16][66];

  const int tid = threadIdx.x;
  const int w = tid >> 6, lane = tid & 63;
  const int head = blockIdx.y;
  const int n0 = blockIdx.x * 64;
  const int qbase = n0 + w*16;
  const int hq = qbase / 48;
  const int wq0 = qbase % 48;
  const int q = lane & 15, g = lane >> 4;

  // Q fragments (B-operand layout: col=q=lane&15, k=g*8+j), scaled by 1/8
  bf16x8 qf[2];
  {
    const __hip_bfloat16* qp = qkvb + (size_t)(qbase + q)*NTOK + head*64 + g*8;
    #pragma unroll
    for (int ks = 0; ks < 2; ++ks){
      bf16x8 t = *(const bf16x8*)(qp + 32*ks);
      #pragma unroll
      for (int j = 0; j < 8; ++j) t[j] = f2b(b2f(t[j]) * 0.125f);
      qf[ks] = t;
    }
  }

  // rel tables via MFMA (x8 to undo the 0.125 Q scale: reference uses unscaled q)
  #pragma unroll
  for (int f = 0; f < 3; ++f){           // rlh[q][hk], hk = f*16 + row
    int grow = hq - (f*16 + q) + 47;     // A-row = lane&15
    f32x4 c = {};
    #pragma unroll
    for (int ks = 0; ks < 2; ++ks){
      bf16x8 a = *(const bf16x8*)(rphb + grow*64 + g*8 + 32*ks);
      c = MFMA16(a, qf[ks], c);
    }
    #pragma unroll
    for (int r = 0; r < 4; ++r) rlh[w][q][f*16 + g*4 + r] = c[r] * 8.0f;
  }
  #pragma unroll
  for (int f = 0; f < 4; ++f){           // rlt[q][u], u = wk - q + 15
    int grow = wq0 + 62 - (f*16 + q);
    if (grow < 0) grow = 0;
    f32x4 c = {};
    #pragma unroll
    for (int ks = 0; ks < 2; ++ks){
      bf16x8 a = *(const bf16x8*)(rpwb + grow*64 + g*8 + 32*ks);
      c = MFMA16(a, qf[ks], c);
    }
    #pragma unroll
    for (int r = 0; r < 4; ++r) rlt[w][q][f*16 + g*4 + r] = c[r] * 8.0f;
  }

  float m_run = -1e30f, l_run = 0.f;
  f32x4 oacc[4] = {};   // lane: O[qrow=g*4+r][d=df*16+q]

  const __hip_bfloat16* kgbase = qkvb + 768 + head*64;
  const __hip_bfloat16* vgbase = Vtg + (size_t)head*64*NTOK;

  for (int ch = 0; ch < 36; ++ch){
    __syncthreads();
    #pragma unroll
    for (int i = 0; i < 2; ++i){
      int e = i*256 + tid;
      int row = e >> 3, s = e & 7;
      int e0 = i*256 + w*64;
      GLOAD16(kgbase + (size_t)(ch*64 + row)*NTOK + (s ^ (row & 7))*8, (char*)Ks + e0*16);
      GLOAD16(vgbase + (size_t)row*NTOK + ch*64 + (s ^ (row & 7))*8,   (char*)Vs + e0*16);
    }
    __syncthreads();

    // St[key][q] = (Q*scale) . K
    f32x4 st[4];
    #pragma unroll
    for (int kf = 0; kf < 4; ++kf){
      int key = kf*16 + q;               // A-row = lane&15
      f32x4 c = {};
      #pragma unroll
      for (int ks = 0; ks < 2; ++ks){
        int slot = (4*ks + g) ^ (key & 7);
        bf16x8 kf8 = *(const bf16x8*)((const char*)Ks + key*128 + slot*16);
        c = MFMA16(kf8, qf[ks], c);
      }
      st[kf] = c;
    }

    // rel-pos bias (chunk spans exactly hk0, hk0+1)
    const int kb64 = ch*64;
    const int hk0 = kb64 / 48;
    const int bnd = (hk0+1)*48;
    const float rh0 = rlh[w][q][hk0];
    const float rh1 = rlh[w][q][hk0+1];
    float sv[4][4];
    #pragma unroll
    for (int kf = 0; kf < 4; ++kf)
      #pragma unroll
      for (int r = 0; r < 4; ++r){
        int keyg = kb64 + kf*16 + g*4 + r;
        bool in1 = keyg >= bnd;
        int wk = keyg - (in1 ? bnd : hk0*48);
        sv[kf][r] = st[kf][r] + (in1 ? rh1 : rh0) + rlt[w][q][wk - q + 15];
      }

    // online softmax over the 4-lane q-group
    float cmax = -1e30f;
    #pragma unroll
    for (int kf = 0; kf < 4; ++kf)
      #pragma unroll
      for (int r = 0; r < 4; ++r) cmax = fmaxf(cmax, sv[kf][r]);
    cmax = fmaxf(cmax, __shfl_xor(cmax, 16));
    cmax = fmaxf(cmax, __shfl_xor(cmax, 32));
    float nm = fmaxf(m_run, cmax);
    float fs = __expf(m_run - nm);
    m_run = nm;
    float p[4][4]; float lsum = 0.f;
    #pragma unroll
    for (int kf = 0; kf < 4; ++kf)
      #pragma unroll
      for (int r = 0; r < 4; ++r){ p[kf][r] = __expf(sv[kf][r] - nm); lsum += p[kf][r]; }
    lsum += __shfl_xor(lsum, 16);
    lsum += __shfl_xor(lsum, 32);
    l_run = l_run * fs + lsum;

    float fr[4];
    #pragma unroll
    for (int r = 0; r < 4; ++r) fr[r] = __shfl(fs, g*4 + r);
    #pragma unroll
    for (int df = 0; df < 4; ++df)
      #pragma unroll
      for (int r = 0; r < 4; ++r) oacc[df][r] *= fr[r];

    // pack P -> bf16 pairs; redistribute to PV A-frag layout
    unsigned bb[4][2];
    #pragma unroll
    for (int kf = 0; kf < 4; ++kf){
      bb[kf][0] = cvtpk(p[kf][0], p[kf][1]);
      bb[kf][1] = cvtpk(p[kf][2], p[kf][3]);
    }
    const int s0 = q + ((g & 1) << 5), s1 = s0 + 16;
    const bool hi = (g >> 1);
    #pragma unroll
    for (int ks = 0; ks < 2; ++ks){
      int ka = 2*ks, kb = 2*ks+1;
      unsigned wa0 = __shfl((int)bb[ka][0], s0), wa1 = __shfl((int)bb[ka][1], s0);
      unsigned wa2 = __shfl((int)bb[ka][0], s1), wa3 = __shfl((int)bb[ka][1], s1);
      unsigned wb0 = __shfl((int)bb[kb][0], s0), wb1 = __shfl((int)bb[kb][1], s0);
      unsigned wb2 = __shfl((int)bb[kb][0], s1), wb3 = __shfl((int)bb[kb][1], s1);
      union { unsigned u[4]; bf16x8 v; } pu;
      pu.u[0] = hi ? wb0 : wa0; pu.u[1] = hi ? wb1 : wa1;
      pu.u[2] = hi ? wb2 : wa2; pu.u[3] = hi ? wb3 : wa3;
      #pragma unroll
      for (int df = 0; df < 4; ++df){
        int d = df*16 + q;                 // B-col = lane&15
        int slot = (4*ks + g) ^ (d & 7);
        bf16x8 vf8 = *(const bf16x8*)((const char*)Vs + d*128 + slot*16);
        oacc[df] = MFMA16(pu.v, vf8, oacc[df]);
      }
    }
  }

  float rl[4];
  #pragma unroll
  for (int r = 0; r < 4; ++r) rl[r] = 1.0f / __shfl(l_run, g*4 + r);
  #pragma unroll
  for (int df = 0; df < 4; ++df)
    #pragma unroll
    for (int r = 0; r < 4; ++r)
      attb[(size_t)(qbase + g*4 + r)*CDIM + head*64 + df*16 + q] =
          __float2bfloat16(oacc[df][r] * rl[r]);
}

extern "C" void kernel_launch(void* const* d_in, const int* in_sizes, int n_in,
                              void* d_out, int out_size, void* d_ws, size_t ws_size,
                              hipStream_t stream) {
  const float* x      = (const float*)d_in[0];
  const float* ln1_g  = (const float*)d_in[1];
  const float* ln1_b  = (const float*)d_in[2];
  const float* qkv_w  = (const float*)d_in[3];
  const float* qkv_b  = (const float*)d_in[4];
  const float* rph    = (const float*)d_in[5];
  const float* rpw    = (const float*)d_in[6];
  const float* proj_w = (const float*)d_in[7];
  const float* proj_b = (const float*)d_in[8];
  const float* ln2_g  = (const float*)d_in[9];
  const float* ln2_b  = (const float*)d_in[10];
  const float* mlp_w1 = (const float*)d_in[11];
  const float* mlp_b1 = (const float*)d_in[12];
  const float* mlp_w2 = (const float*)d_in[13];
  const float* mlp_b2 = (const float*)d_in[14];

  char* ws = (char*)d_ws;
  __hip_bfloat16* xnb  = (__hip_bfloat16*)(ws);                  // 2304x768 bf16
  __hip_bfloat16* qkvb = (__hip_bfloat16*)(ws + 3538944);        // 2304x2304 bf16
  __hip_bfloat16* attb = (__hip_bfloat16*)(ws + 14155776);       // 2304x768 bf16
  __hip_bfloat16* Vtg  = (__hip_bfloat16*)(ws + 17694720);       // 12x64x2304 bf16
  float*          x1f  = (float*)         (ws + 21233664);       // 2304x768 f32
  __hip_bfloat16* wTb  = (__hip_bfloat16*)(ws + 28311552);       // up to 3072x768 bf16
  __hip_bfloat16* rphb = (__hip_bfloat16*)(ws + 33030144);       // 95x64 bf16
  __hip_bfloat16* rpwb = (__hip_bfloat16*)(ws + 33042432);
  __hip_bfloat16* hb   = (__hip_bfloat16*)(ws + 33054720);       // 2304x3072 bf16

  castrp<<<24, 256, 0, stream>>>(rph, rpw, rphb, rpwb);
  ln_kernel<<<NTOK, 256, 0, stream>>>(x, ln1_g, ln1_b, xnb);

  wt_kernel<<<dim3(2304/32, 768/32), 256, 0, stream>>>(qkv_w, wTb, 768, 2304);
  gemm_bf16<0,0,1><<<dim3(18, 18), 256, 0, stream>>>(
      xnb, wTb, qkv_b, nullptr, qkvb, NTOK, 768, 2304);

  vt_kernel<<<dim3(72, 2, 12), 256, 0, stream>>>(qkvb, Vtg);
  attn_mfma<<<dim3(36, 12), 256, 0, stream>>>(qkvb, Vtg, rphb, rpwb, attb);

  wt_kernel<<<dim3(768/32, 768/32), 256, 0, stream>>>(proj_w, wTb, 768, 768);
  gemm_bf16<0,1,0><<<dim3(6, 18), 256, 0, stream>>>(
      attb, wTb, proj_b, x, x1f, NTOK, 768, 768);

  ln_kernel<<<NTOK, 256, 0, stream>>>(x1f, ln2_g, ln2_b, xnb);

  wt_kernel<<<dim3(3072/32, 768/32), 256, 0, stream>>>(mlp_w1, wTb, 768, 3072);
  gemm_bf16<1,0,1><<<dim3(24, 18), 256, 0, stream>>>(
      xnb, wTb, mlp_b1, nullptr, hb, NTOK, 768, 3072);

  wt_kernel<<<dim3(768/32, 3072/32), 256, 0, stream>>>(mlp_w2, wTb, 3072, 768);
  gemm_bf16<0,1,0><<<dim3(6, 18), 256, 0, stream>>>(
      hb, wTb, mlp_b2, x1f, d_out, NTOK, 3072, 768);
}

// Round 5
// 290.361 us; speedup vs baseline: 7.2955x; 1.1694x over previous
//
#include <hip/hip_runtime.h>
#include <hip/hip_bf16.h>
#include <math.h>

#define NTOK 2304
#define CDIM 768
#define NPART 3

typedef __attribute__((ext_vector_type(8))) short bf16x8;
typedef __attribute__((ext_vector_type(4))) float f32x4;

#define MFMA16(a,b,c) __builtin_amdgcn_mfma_f32_16x16x32_bf16(a,b,c,0,0,0)
#define GLOAD16(g, l) __builtin_amdgcn_global_load_lds( \
    (const __attribute__((address_space(1))) void*)(g), \
    (__attribute__((address_space(3))) void*)(l), 16, 0, 0)

__device__ __forceinline__ short f2b(float f){
  __hip_bfloat16 h = __float2bfloat16(f);
  short s; __builtin_memcpy(&s, &h, 2); return s;
}
__device__ __forceinline__ float b2f(short s){
  __hip_bfloat16 h; __builtin_memcpy(&h, &s, 2); return __bfloat162float(h);
}
__device__ __forceinline__ unsigned cvtpk(float a, float b){
  unsigned r;
  asm("v_cvt_pk_bf16_f32 %0, %1, %2" : "=v"(r) : "v"(a), "v"(b));
  return r;
}
__device__ __forceinline__ float wsum(float v){
  #pragma unroll
  for (int o = 32; o > 0; o >>= 1) v += __shfl_xor(v, o);
  return v;
}

// ---------------- LayerNorm (f32 or bf16 in, bf16 out) ----------------
template<int IBF>
__global__ __launch_bounds__(256) void ln_kernel(const void* __restrict__ xv,
    const float* __restrict__ g, const float* __restrict__ b,
    __hip_bfloat16* __restrict__ out){
  __shared__ float sm[4];
  const int row = blockIdx.x, tid = threadIdx.x;
  float v0, v1, v2;
  if (IBF){
    const short* xr = (const short*)xv + (size_t)row * CDIM;
    v0 = b2f(xr[tid]); v1 = b2f(xr[tid+256]); v2 = b2f(xr[tid+512]);
  } else {
    const float* xr = (const float*)xv + (size_t)row * CDIM;
    v0 = xr[tid]; v1 = xr[tid+256]; v2 = xr[tid+512];
  }
  float s = wsum(v0+v1+v2);
  if ((tid & 63)==0) sm[tid>>6] = s;
  __syncthreads();
  float mean = (sm[0]+sm[1]+sm[2]+sm[3]) * (1.0f/CDIM);
  __syncthreads();
  float d0=v0-mean, d1=v1-mean, d2=v2-mean;
  float ss = wsum(d0*d0+d1*d1+d2*d2);
  if ((tid&63)==0) sm[tid>>6] = ss;
  __syncthreads();
  float rstd = rsqrtf((sm[0]+sm[1]+sm[2]+sm[3])*(1.0f/CDIM) + 1e-6f);
  __hip_bfloat16* o = out + (size_t)row*CDIM;
  o[tid]     = __float2bfloat16(d0*rstd*g[tid]     + b[tid]);
  o[tid+256] = __float2bfloat16(d1*rstd*g[tid+256] + b[tid+256]);
  o[tid+512] = __float2bfloat16(d2*rstd*g[tid+512] + b[tid+512]);
}

// ------------- weight transpose+cast: W f32[K][N] -> Wt bf16[N][K] -------------
__global__ __launch_bounds__(256) void wt_kernel(const float* __restrict__ W,
    __hip_bfloat16* __restrict__ Wt, int K, int N){
  __shared__ float t[32][33];
  const int n0 = blockIdx.x*32, k0 = blockIdx.y*32;
  const int c = threadIdx.x & 31, r0 = threadIdx.x >> 5;
  #pragma unroll
  for (int i = 0; i < 4; ++i){
    int r = r0 + i*8;
    t[r][c] = W[(size_t)(k0 + r)*N + n0 + c];
  }
  __syncthreads();
  #pragma unroll
  for (int i = 0; i < 4; ++i){
    int r = r0 + i*8;
    Wt[(size_t)(n0 + r)*K + k0 + c] = __float2bfloat16(t[c][r]);
  }
}

// ------------- rel-pos cast f32 -> bf16 (both tables) -------------
__global__ __launch_bounds__(256) void castrp(const float* __restrict__ rph,
    const float* __restrict__ rpw, __hip_bfloat16* __restrict__ rphb,
    __hip_bfloat16* __restrict__ rpwb){
  int i = blockIdx.x*256 + threadIdx.x;
  if (i < 95*64){ rphb[i] = __float2bfloat16(rph[i]); rpwb[i] = __float2bfloat16(rpw[i]); }
}

// ------------- V transpose: qkvb[n][1536+h*64+d] -> Vtg[h][d][n] -------------
__global__ __launch_bounds__(256) void vt_kernel(const __hip_bfloat16* __restrict__ qkvb,
    __hip_bfloat16* __restrict__ Vtg){
  __shared__ __hip_bfloat16 t[32][33];
  const int n0 = blockIdx.x*32, d0 = blockIdx.y*32, h = blockIdx.z;
  const int c = threadIdx.x & 31, r0 = threadIdx.x >> 5;
  #pragma unroll
  for (int i = 0; i < 4; ++i){
    int r = r0 + i*8;
    t[r][c] = qkvb[(size_t)(n0+r)*NTOK + 1536 + h*64 + d0 + c];
  }
  __syncthreads();
  #pragma unroll
  for (int i = 0; i < 4; ++i){
    int r = r0 + i*8;
    Vtg[((size_t)h*64 + d0 + r)*NTOK + n0 + c] = t[c][r];
  }
}

// ------------- bf16 MFMA GEMM, 2-phase prefetch, templated wave tile -------------
// C[M][N] = A[M][K] @ Bt[N][K]^T + bias  (+gelu)(+res).  Block = 2x2 waves.
template<int WM, int WN, int ACT, int RES, int RBF, int OBF>
__global__ __launch_bounds__(256) void gemm_bf16(
    const __hip_bfloat16* __restrict__ A, const __hip_bfloat16* __restrict__ Bt,
    const float* __restrict__ bias, const void* __restrict__ res,
    void* __restrict__ Cout, int M, int K, int N){
  constexpr int BM = 2*WM, BN = 2*WN;
  constexpr int ROUNDS = (BM+BN)/64, AR = BM/64;
  __shared__ short As[2][BM*32];
  __shared__ short Bs[2][BN*32];
  const int tid = threadIdx.x;
  const int w = tid >> 6, lane = tid & 63;
  const int wr = w >> 1, wc = w & 1;
  const int bm = blockIdx.y*BM, bn = blockIdx.x*BN;
  const int l15 = lane & 15, l4 = lane >> 4;
  f32x4 acc[WM/16][WN/16] = {};

  const int ra = wr*WM + l15;
  const int rb = wc*WN + l15;
  const int kswa = l4 ^ ((ra>>1)&3);
  const int kswb = l4 ^ ((rb>>1)&3);

  auto STAGE = [&](int buf, int k0){
    #pragma unroll
    for (int r = 0; r < ROUNDS; ++r){
      if (r < AR){
        int e = r*256 + tid;
        int row = e >> 2, s = e & 3, gs = s ^ ((row>>1)&3);
        GLOAD16(A + (size_t)(bm+row)*K + k0 + gs*8, (char*)As[buf] + (r*256 + w*64)*16);
      } else {
        int e = (r-AR)*256 + tid;
        int row = e >> 2, s = e & 3, gs = s ^ ((row>>1)&3);
        GLOAD16(Bt + (size_t)(bn+row)*K + k0 + gs*8, (char*)Bs[buf] + ((r-AR)*256 + w*64)*16);
      }
    }
  };

  const int nt = K/32;
  STAGE(0, 0);
  __syncthreads();
  int cur = 0;
  for (int t = 0; t < nt; ++t){
    if (t+1 < nt) STAGE(cur^1, (t+1)*32);
    bf16x8 af[WM/16], bfr[WN/16];
    #pragma unroll
    for (int m = 0; m < WM/16; ++m)
      af[m] = *(const bf16x8*)((const char*)As[cur] + (ra + m*16)*64 + kswa*16);
    #pragma unroll
    for (int n = 0; n < WN/16; ++n)
      bfr[n] = *(const bf16x8*)((const char*)Bs[cur] + (rb + n*16)*64 + kswb*16);
    #pragma unroll
    for (int m = 0; m < WM/16; ++m)
      #pragma unroll
      for (int n = 0; n < WN/16; ++n)
        acc[m][n] = MFMA16(af[m], bfr[n], acc[m][n]);
    __syncthreads();
    cur ^= 1;
  }

  const int crow = bm + wr*WM + l4*4;
  const int ccol = bn + wc*WN + l15;
  #pragma unroll
  for (int m = 0; m < WM/16; ++m){
    #pragma unroll
    for (int n = 0; n < WN/16; ++n){
      #pragma unroll
      for (int r = 0; r < 4; ++r){
        int rr = crow + m*16 + r, cc = ccol + n*16;
        float v = acc[m][n][r] + bias[cc];
        if (ACT == 1) v = 0.5f * v * (1.0f + erff(v * 0.70710678118654752f));
        if (RES){
          if (RBF) v += b2f(((const short*)res)[(size_t)rr*N + cc]);
          else     v += ((const float*)res)[(size_t)rr*N + cc];
        }
        if (OBF) ((__hip_bfloat16*)Cout)[(size_t)rr*N + cc] = __float2bfloat16(v);
        else     ((float*)Cout)[(size_t)rr*N + cc] = v;
      }
    }
  }
}

// ------------- MFMA flash attention, KV-split x3, decomposed rel-pos -------------
// grid (36, 12, 3): 64 queries/block (4 waves x 16q), part z does chunks [12z,12z+12).
__global__ __launch_bounds__(256) void attn_mfma(
    const __hip_bfloat16* __restrict__ qkvb,  // [2304][2304]
    const __hip_bfloat16* __restrict__ Vtg,   // [12][64][2304]
    const __hip_bfloat16* __restrict__ rphb,  // [95][64]
    const __hip_bfloat16* __restrict__ rpwb,  // [95][64]
    __hip_bfloat16* __restrict__ Opart,       // [3][2304][768] unnormalized
    float2* __restrict__ ml){                 // [3][12][2304]
  __shared__ short Ks[64*64];        // [key][d], 16B slot s holds global slot s^(key&7)
  __shared__ short Vs[64*64];        // [d][key], slot s holds global key-slot s^(d&7)
  __shared__ short rlh[4][16][50];
  __shared__ short rlt[4][16][66];

  const int tid = threadIdx.x;
  const int w = tid >> 6, lane = tid & 63;
  const int head = blockIdx.y;
  const int part = blockIdx.z;
  const int n0 = blockIdx.x * 64;
  const int qbase = n0 + w*16;
  const int hq = qbase / 48;
  const int wq0 = qbase % 48;
  const int q = lane & 15, g = lane >> 4;

  // Q fragments (B-operand layout: col=q=lane&15, k=g*8+j), scaled by 1/8
  bf16x8 qf[2];
  {
    const __hip_bfloat16* qp = qkvb + (size_t)(qbase + q)*NTOK + head*64 + g*8;
    #pragma unroll
    for (int ks = 0; ks < 2; ++ks){
      bf16x8 t = *(const bf16x8*)(qp + 32*ks);
      #pragma unroll
      for (int j = 0; j < 8; ++j) t[j] = f2b(b2f(t[j]) * 0.125f);
      qf[ks] = t;
    }
  }

  // rel tables via MFMA (x8 undoes the 0.125 Q scale; reference uses unscaled q)
  #pragma unroll
  for (int f = 0; f < 3; ++f){           // rlh[q][hk], hk = f*16 + row
    int grow = hq - (f*16 + q) + 47;
    f32x4 c = {};
    #pragma unroll
    for (int ks = 0; ks < 2; ++ks){
      bf16x8 a = *(const bf16x8*)(rphb + grow*64 + g*8 + 32*ks);
      c = MFMA16(a, qf[ks], c);
    }
    #pragma unroll
    for (int r = 0; r < 4; ++r) rlh[w][q][f*16 + g*4 + r] = f2b(c[r] * 8.0f);
  }
  #pragma unroll
  for (int f = 0; f < 4; ++f){           // rlt[q][u], u = wk - q + 15
    int grow = wq0 + 62 - (f*16 + q);
    if (grow < 0) grow = 0;
    f32x4 c = {};
    #pragma unroll
    for (int ks = 0; ks < 2; ++ks){
      bf16x8 a = *(const bf16x8*)(rpwb + grow*64 + g*8 + 32*ks);
      c = MFMA16(a, qf[ks], c);
    }
    #pragma unroll
    for (int r = 0; r < 4; ++r) rlt[w][q][f*16 + g*4 + r] = f2b(c[r] * 8.0f);
  }

  float m_run = -1e30f, l_run = 0.f;
  f32x4 oacc[4] = {};   // lane: O[qrow=g*4+r][d=df*16+q]

  const __hip_bfloat16* kgbase = qkvb + 768 + head*64;
  const __hip_bfloat16* vgbase = Vtg + (size_t)head*64*NTOK;

  for (int ci = 0; ci < 36/NPART; ++ci){
    const int ch = part*(36/NPART) + ci;
    __syncthreads();
    #pragma unroll
    for (int i = 0; i < 2; ++i){
      int e = i*256 + tid;
      int row = e >> 3, s = e & 7;
      int e0 = i*256 + w*64;
      GLOAD16(kgbase + (size_t)(ch*64 + row)*NTOK + (s ^ (row & 7))*8, (char*)Ks + e0*16);
      GLOAD16(vgbase + (size_t)row*NTOK + ch*64 + (s ^ (row & 7))*8,   (char*)Vs + e0*16);
    }
    __syncthreads();

    // St[key][q] = (Q*scale) . K
    f32x4 st[4];
    #pragma unroll
    for (int kf = 0; kf < 4; ++kf){
      int key = kf*16 + q;
      f32x4 c = {};
      #pragma unroll
      for (int ks = 0; ks < 2; ++ks){
        int slot = (4*ks + g) ^ (key & 7);
        bf16x8 kf8 = *(const bf16x8*)((const char*)Ks + key*128 + slot*16);
        c = MFMA16(kf8, qf[ks], c);
      }
      st[kf] = c;
    }

    // rel-pos bias (chunk spans exactly hk0, hk0+1)
    const int kb64 = ch*64;
    const int hk0 = kb64 / 48;
    const int bnd = (hk0+1)*48;
    const float rh0 = b2f(rlh[w][q][hk0]);
    const float rh1 = b2f(rlh[w][q][hk0+1]);
    float sv[4][4];
    #pragma unroll
    for (int kf = 0; kf < 4; ++kf)
      #pragma unroll
      for (int r = 0; r < 4; ++r){
        int keyg = kb64 + kf*16 + g*4 + r;
        bool in1 = keyg >= bnd;
        int wk = keyg - (in1 ? bnd : hk0*48);
        sv[kf][r] = st[kf][r] + (in1 ? rh1 : rh0) + b2f(rlt[w][q][wk - q + 15]);
      }

    // online softmax over the 4-lane q-group
    float cmax = -1e30f;
    #pragma unroll
    for (int kf = 0; kf < 4; ++kf)
      #pragma unroll
      for (int r = 0; r < 4; ++r) cmax = fmaxf(cmax, sv[kf][r]);
    cmax = fmaxf(cmax, __shfl_xor(cmax, 16));
    cmax = fmaxf(cmax, __shfl_xor(cmax, 32));
    float nm = fmaxf(m_run, cmax);
    float fs = __expf(m_run - nm);
    m_run = nm;
    float p[4][4]; float lsum = 0.f;
    #pragma unroll
    for (int kf = 0; kf < 4; ++kf)
      #pragma unroll
      for (int r = 0; r < 4; ++r){ p[kf][r] = __expf(sv[kf][r] - nm); lsum += p[kf][r]; }
    lsum += __shfl_xor(lsum, 16);
    lsum += __shfl_xor(lsum, 32);
    l_run = l_run * fs + lsum;

    float fr[4];
    #pragma unroll
    for (int r = 0; r < 4; ++r) fr[r] = __shfl(fs, g*4 + r);
    #pragma unroll
    for (int df = 0; df < 4; ++df)
      #pragma unroll
      for (int r = 0; r < 4; ++r) oacc[df][r] *= fr[r];

    // pack P -> bf16 pairs; redistribute to PV A-frag layout
    unsigned bb[4][2];
    #pragma unroll
    for (int kf = 0; kf < 4; ++kf){
      bb[kf][0] = cvtpk(p[kf][0], p[kf][1]);
      bb[kf][1] = cvtpk(p[kf][2], p[kf][3]);
    }
    const int s0 = q + ((g & 1) << 5), s1 = s0 + 16;
    const bool hi = (g >> 1);
    #pragma unroll
    for (int ks = 0; ks < 2; ++ks){
      int ka = 2*ks, kb = 2*ks+1;
      unsigned wa0 = __shfl((int)bb[ka][0], s0), wa1 = __shfl((int)bb[ka][1], s0);
      unsigned wa2 = __shfl((int)bb[ka][0], s1), wa3 = __shfl((int)bb[ka][1], s1);
      unsigned wb0 = __shfl((int)bb[kb][0], s0), wb1 = __shfl((int)bb[kb][1], s0);
      unsigned wb2 = __shfl((int)bb[kb][0], s1), wb3 = __shfl((int)bb[kb][1], s1);
      union { unsigned u[4]; bf16x8 v; } pu;
      pu.u[0] = hi ? wb0 : wa0; pu.u[1] = hi ? wb1 : wa1;
      pu.u[2] = hi ? wb2 : wa2; pu.u[3] = hi ? wb3 : wa3;
      #pragma unroll
      for (int df = 0; df < 4; ++df){
        int d = df*16 + q;
        int slot = (4*ks + g) ^ (d & 7);
        bf16x8 vf8 = *(const bf16x8*)((const char*)Vs + d*128 + slot*16);
        oacc[df] = MFMA16(pu.v, vf8, oacc[df]);
      }
    }
  }

  // write unnormalized partial O + (m,l) per q-row
  __hip_bfloat16* op = Opart + (size_t)part*NTOK*CDIM;
  #pragma unroll
  for (int df = 0; df < 4; ++df)
    #pragma unroll
    for (int r = 0; r < 4; ++r)
      op[(size_t)(qbase + g*4 + r)*CDIM + head*64 + df*16 + q] =
          __float2bfloat16(oacc[df][r]);
  if (g == 0)
    ml[(size_t)part*12*NTOK + head*NTOK + qbase + q] = make_float2(m_run, l_run);
}

// ------------- merge the 3 KV-split partials -------------
__global__ __launch_bounds__(256) void merge_kernel(
    const __hip_bfloat16* __restrict__ Opart, const float2* __restrict__ ml,
    __hip_bfloat16* __restrict__ attb){
  const int n = blockIdx.x, tid = threadIdx.x;
  #pragma unroll
  for (int j = 0; j < 3; ++j){
    int c = tid + j*256;
    int h = c >> 6;
    float2 a = ml[h*NTOK + n];
    float2 b = ml[12*NTOK + h*NTOK + n];
    float2 d = ml[2*12*NTOK + h*NTOK + n];
    float M = fmaxf(a.x, fmaxf(b.x, d.x));
    float e0 = __expf(a.x - M), e1 = __expf(b.x - M), e2 = __expf(d.x - M);
    float L = a.y*e0 + b.y*e1 + d.y*e2;
    float o0 = __bfloat162float(Opart[(size_t)n*CDIM + c]);
    float o1 = __bfloat162float(Opart[(size_t)NTOK*CDIM + n*CDIM + c]);
    float o2 = __bfloat162float(Opart[(size_t)2*NTOK*CDIM + n*CDIM + c]);
    attb[(size_t)n*CDIM + c] = __float2bfloat16((o0*e0 + o1*e1 + o2*e2) / L);
  }
}

extern "C" void kernel_launch(void* const* d_in, const int* in_sizes, int n_in,
                              void* d_out, int out_size, void* d_ws, size_t ws_size,
                              hipStream_t stream) {
  const float* x      = (const float*)d_in[0];
  const float* ln1_g  = (const float*)d_in[1];
  const float* ln1_b  = (const float*)d_in[2];
  const float* qkv_w  = (const float*)d_in[3];
  const float* qkv_b  = (const float*)d_in[4];
  const float* rph    = (const float*)d_in[5];
  const float* rpw    = (const float*)d_in[6];
  const float* proj_w = (const float*)d_in[7];
  const float* proj_b = (const float*)d_in[8];
  const float* ln2_g  = (const float*)d_in[9];
  const float* ln2_b  = (const float*)d_in[10];
  const float* mlp_w1 = (const float*)d_in[11];
  const float* mlp_b1 = (const float*)d_in[12];
  const float* mlp_w2 = (const float*)d_in[13];
  const float* mlp_b2 = (const float*)d_in[14];

  char* ws = (char*)d_ws;
  // layout (bytes), with lifetime-safe aliases:
  __hip_bfloat16* xnb   = (__hip_bfloat16*)(ws);              // 3,538,944
  __hip_bfloat16* qkvb  = (__hip_bfloat16*)(ws + 3538944);    // 10,616,832
  __hip_bfloat16* x1b   = (__hip_bfloat16*)(ws + 3538944);    // alias (qkvb dead after attn)
  __hip_bfloat16* Vtg   = (__hip_bfloat16*)(ws + 14155776);   // 3,538,944
  __hip_bfloat16* qkvT  = (__hip_bfloat16*)(ws + 17694720);   // 3,538,944
  __hip_bfloat16* attb  = (__hip_bfloat16*)(ws + 17694720);   // alias (qkvT dead after qkv gemm)
  __hip_bfloat16* projT = (__hip_bfloat16*)(ws + 21233664);   // 1,179,648
  __hip_bfloat16* m1T   = (__hip_bfloat16*)(ws + 22413312);   // 4,718,592
  __hip_bfloat16* m2T   = (__hip_bfloat16*)(ws + 27131904);   // 4,718,592
  __hip_bfloat16* rphb  = (__hip_bfloat16*)(ws + 31850496);   // 12,160
  __hip_bfloat16* rpwb  = (__hip_bfloat16*)(ws + 31862656);   // 12,160
  __hip_bfloat16* Opart = (__hip_bfloat16*)(ws + 31874816);   // 10,616,832
  float2*         mlp_  = (float2*)        (ws + 42491648);   // 663,552
  __hip_bfloat16* hb    = (__hip_bfloat16*)(ws + 31874816);   // alias (Opart/ml dead after merge)

  castrp<<<24, 256, 0, stream>>>(rph, rpw, rphb, rpwb);
  ln_kernel<0><<<NTOK, 256, 0, stream>>>(x, ln1_g, ln1_b, xnb);
  wt_kernel<<<dim3(72, 24), 256, 0, stream>>>(qkv_w, qkvT, 768, 2304);
  wt_kernel<<<dim3(24, 24), 256, 0, stream>>>(proj_w, projT, 768, 768);
  wt_kernel<<<dim3(96, 24), 256, 0, stream>>>(mlp_w1, m1T, 768, 3072);
  wt_kernel<<<dim3(24, 96), 256, 0, stream>>>(mlp_w2, m2T, 3072, 768);

  // qkv = xn @ qkv_w + b   (2304 x 768 x 2304), 64x128 tile
  gemm_bf16<32,64,0,0,0,1><<<dim3(18, 36), 256, 0, stream>>>(
      xnb, qkvT, qkv_b, nullptr, qkvb, NTOK, 768, 2304);

  vt_kernel<<<dim3(72, 2, 12), 256, 0, stream>>>(qkvb, Vtg);
  attn_mfma<<<dim3(36, 12, NPART), 256, 0, stream>>>(qkvb, Vtg, rphb, rpwb, Opart, mlp_);
  merge_kernel<<<NTOK, 256, 0, stream>>>(Opart, mlp_, attb);

  // x1 = x + att @ proj_w + b   (2304 x 768 x 768), 64x64 tile, bf16 out
  gemm_bf16<32,32,0,1,0,1><<<dim3(12, 36), 256, 0, stream>>>(
      attb, projT, proj_b, x, x1b, NTOK, 768, 768);

  ln_kernel<1><<<NTOK, 256, 0, stream>>>(x1b, ln2_g, ln2_b, xnb);

  // h = gelu(y @ mlp_w1 + b)   (2304 x 768 x 3072), 64x128 tile
  gemm_bf16<32,64,1,0,0,1><<<dim3(24, 36), 256, 0, stream>>>(
      xnb, m1T, mlp_b1, nullptr, hb, NTOK, 768, 3072);

  // out = x1 + h @ mlp_w2 + b  (2304 x 3072 x 768), 64x64 tile, f32 out
  gemm_bf16<32,32,0,1,1,0><<<dim3(12, 36), 256, 0, stream>>>(
      hb, m2T, mlp_b2, x1b, d_out, NTOK, 3072, 768);
}

// Round 7
// 264.438 us; speedup vs baseline: 8.0106x; 1.0980x over previous
//
#include <hip/hip_runtime.h>
#include <hip/hip_bf16.h>
#include <math.h>

#define NTOK 2304
#define CDIM 768

typedef __attribute__((ext_vector_type(8))) short bf16x8;
typedef __attribute__((ext_vector_type(4))) float f32x4;

#define MFMA16(a,b,c) __builtin_amdgcn_mfma_f32_16x16x32_bf16(a,b,c,0,0,0)
#define GLOAD16(g, l) __builtin_amdgcn_global_load_lds( \
    (const __attribute__((address_space(1))) void*)(g), \
    (__attribute__((address_space(3))) void*)(l), 16, 0, 0)

__device__ __forceinline__ short f2b(float f){
  __hip_bfloat16 h = __float2bfloat16(f);
  short s; __builtin_memcpy(&s, &h, 2); return s;
}
__device__ __forceinline__ float b2f(short s){
  __hip_bfloat16 h; __builtin_memcpy(&h, &s, 2); return __bfloat162float(h);
}
__device__ __forceinline__ unsigned cvtpk(float a, float b){
  unsigned r;
  asm("v_cvt_pk_bf16_f32 %0, %1, %2" : "=v"(r) : "v"(a), "v"(b));
  return r;
}
__device__ __forceinline__ float wsum(float v){
  #pragma unroll
  for (int o = 32; o > 0; o >>= 1) v += __shfl_xor(v, o);
  return v;
}

// ---------------- LayerNorm (f32 in, bf16 out) ----------------
__global__ __launch_bounds__(256) void ln_kernel(const float* __restrict__ x,
    const float* __restrict__ g, const float* __restrict__ b,
    __hip_bfloat16* __restrict__ out){
  __shared__ float sm[4];
  const int row = blockIdx.x, tid = threadIdx.x;
  const float* xr = x + (size_t)row * CDIM;
  float v0 = xr[tid], v1 = xr[tid+256], v2 = xr[tid+512];
  float s = wsum(v0+v1+v2);
  if ((tid & 63)==0) sm[tid>>6] = s;
  __syncthreads();
  float mean = (sm[0]+sm[1]+sm[2]+sm[3]) * (1.0f/CDIM);
  __syncthreads();
  float d0=v0-mean, d1=v1-mean, d2=v2-mean;
  float ss = wsum(d0*d0+d1*d1+d2*d2);
  if ((tid&63)==0) sm[tid>>6] = ss;
  __syncthreads();
  float rstd = rsqrtf((sm[0]+sm[1]+sm[2]+sm[3])*(1.0f/CDIM) + 1e-6f);
  __hip_bfloat16* o = out + (size_t)row*CDIM;
  o[tid]     = __float2bfloat16(d0*rstd*g[tid]     + b[tid]);
  o[tid+256] = __float2bfloat16(d1*rstd*g[tid+256] + b[tid+256]);
  o[tid+512] = __float2bfloat16(d2*rstd*g[tid+512] + b[tid+512]);
}

// ---------------- fused prep: 4x weight transpose+cast + relpos cast ---------
__device__ __forceinline__ void wt_tile(const float* __restrict__ W,
    __hip_bfloat16* __restrict__ Wt, int K, int N, int tx, int ty,
    float (*t)[33], int tid){
  const int n0 = tx*32, k0 = ty*32;
  const int c = tid & 31, r0 = tid >> 5;
  #pragma unroll
  for (int i = 0; i < 4; ++i){
    int r = r0 + i*8;
    t[r][c] = W[(size_t)(k0 + r)*N + n0 + c];
  }
  __syncthreads();
  #pragma unroll
  for (int i = 0; i < 4; ++i){
    int r = r0 + i*8;
    Wt[(size_t)(n0 + r)*K + k0 + c] = __float2bfloat16(t[c][r]);
  }
}

__global__ __launch_bounds__(256) void prep_kernel(
    const float* __restrict__ qkv_w, const float* __restrict__ proj_w,
    const float* __restrict__ m1w, const float* __restrict__ m2w,
    const float* __restrict__ rph, const float* __restrict__ rpw,
    __hip_bfloat16* __restrict__ qkvT, __hip_bfloat16* __restrict__ projT,
    __hip_bfloat16* __restrict__ m1T, __hip_bfloat16* __restrict__ m2T,
    __hip_bfloat16* __restrict__ rphb, __hip_bfloat16* __restrict__ rpwb){
  __shared__ float t[32][33];
  int id = blockIdx.x, tid = threadIdx.x;
  if (id < 1728)      wt_tile(qkv_w, qkvT, 768, 2304, id%72, id/72, t, tid);
  else if (id < 2304){ id -= 1728; wt_tile(proj_w, projT, 768, 768, id%24, id/24, t, tid); }
  else if (id < 4608){ id -= 2304; wt_tile(m1w, m1T, 768, 3072, id%96, id/96, t, tid); }
  else if (id < 6912){ id -= 4608; wt_tile(m2w, m2T, 3072, 768, id%24, id/24, t, tid); }
  else {
    int i = (id - 6912)*256 + tid;
    if (i < 95*64){ rphb[i] = __float2bfloat16(rph[i]); rpwb[i] = __float2bfloat16(rpw[i]); }
  }
}

// ------------- V transpose: qkvb[n][1536+h*64+d] -> Vtg[h][d][n] -------------
__global__ __launch_bounds__(256) void vt_kernel(const __hip_bfloat16* __restrict__ qkvb,
    __hip_bfloat16* __restrict__ Vtg){
  __shared__ __hip_bfloat16 t[32][33];
  const int n0 = blockIdx.x*32, d0 = blockIdx.y*32, h = blockIdx.z;
  const int c = threadIdx.x & 31, r0 = threadIdx.x >> 5;
  #pragma unroll
  for (int i = 0; i < 4; ++i){
    int r = r0 + i*8;
    t[r][c] = qkvb[(size_t)(n0+r)*NTOK + 1536 + h*64 + d0 + c];
  }
  __syncthreads();
  #pragma unroll
  for (int i = 0; i < 4; ++i){
    int r = r0 + i*8;
    Vtg[((size_t)h*64 + d0 + r)*NTOK + n0 + c] = t[c][r];
  }
}

// ------------- bf16 MFMA GEMM, 128x128 tile, 2-phase prefetch, opt split-K ----
// PARTIAL=0: C=bf16(A@Bt^T + bias [gelu]); PARTIAL=1: f32 partial (no bias).
template<int ACT, int PARTIAL>
__global__ __launch_bounds__(256) void gemm_bf16(
    const __hip_bfloat16* __restrict__ A, const __hip_bfloat16* __restrict__ Bt,
    const float* __restrict__ bias, void* __restrict__ Cout,
    int M, int K, int N, int kst){
  __shared__ short As[2][128*32];
  __shared__ short Bs[2][128*32];
  const int tid = threadIdx.x;
  const int w = tid >> 6, lane = tid & 63;
  const int wr = w >> 1, wc = w & 1;
  const int bm = blockIdx.y*128, bn = blockIdx.x*128;
  const int kbase = blockIdx.z * kst * 32;
  const int l15 = lane & 15, l4 = lane >> 4;
  f32x4 acc[4][4] = {};

  const int ra = wr*64 + l15;
  const int rb = wc*64 + l15;
  const int kswa = l4 ^ ((ra>>1)&3);
  const int kswb = l4 ^ ((rb>>1)&3);

  auto STAGE = [&](int buf, int k0){
    #pragma unroll
    for (int r = 0; r < 4; ++r){
      if (r < 2){
        int e = r*256 + tid;
        int row = e >> 2, s = e & 3, gs = s ^ ((row>>1)&3);
        GLOAD16(A + (size_t)(bm+row)*K + k0 + gs*8, (char*)As[buf] + (r*256 + w*64)*16);
      } else {
        int e = (r-2)*256 + tid;
        int row = e >> 2, s = e & 3, gs = s ^ ((row>>1)&3);
        GLOAD16(Bt + (size_t)(bn+row)*K + k0 + gs*8, (char*)Bs[buf] + ((r-2)*256 + w*64)*16);
      }
    }
  };

  STAGE(0, kbase);
  __syncthreads();
  int cur = 0;
  for (int t = 0; t < kst; ++t){
    if (t+1 < kst) STAGE(cur^1, kbase + (t+1)*32);
    bf16x8 af[4], bfr[4];
    #pragma unroll
    for (int m = 0; m < 4; ++m)
      af[m] = *(const bf16x8*)((const char*)As[cur] + (ra + m*16)*64 + kswa*16);
    #pragma unroll
    for (int n = 0; n < 4; ++n)
      bfr[n] = *(const bf16x8*)((const char*)Bs[cur] + (rb + n*16)*64 + kswb*16);
    #pragma unroll
    for (int m = 0; m < 4; ++m)
      #pragma unroll
      for (int n = 0; n < 4; ++n)
        acc[m][n] = MFMA16(af[m], bfr[n], acc[m][n]);
    __syncthreads();
    cur ^= 1;
  }

  const int crow = bm + wr*64 + l4*4;
  const int ccol = bn + wc*64 + l15;
  float* Cp = (float*)Cout + (size_t)blockIdx.z*M*N;
  #pragma unroll
  for (int m = 0; m < 4; ++m){
    #pragma unroll
    for (int n = 0; n < 4; ++n){
      #pragma unroll
      for (int r = 0; r < 4; ++r){
        int rr = crow + m*16 + r, cc = ccol + n*16;
        if (PARTIAL){
          Cp[(size_t)rr*N + cc] = acc[m][n][r];
        } else {
          float v = acc[m][n][r] + bias[cc];
          if (ACT == 1) v = 0.5f * v * (1.0f + erff(v * 0.70710678118654752f));
          ((__hip_bfloat16*)Cout)[(size_t)rr*N + cc] = __float2bfloat16(v);
        }
      }
    }
  }
}

// ------------- MFMA flash attention, KV-split x3, reg-hoisted rel-pos --------
// grid (36, 12, 3): 64 queries/block (4 waves x 16q), part z does chunks [12z,12z+12)
__global__ __launch_bounds__(256) void attn_mfma(
    const __hip_bfloat16* __restrict__ qkvb,  // [2304][2304]
    const __hip_bfloat16* __restrict__ Vtg,   // [12][64][2304]
    const __hip_bfloat16* __restrict__ rphb,  // [95][64]
    const __hip_bfloat16* __restrict__ rpwb,  // [95][64]
    __hip_bfloat16* __restrict__ Opart,       // [3][2304][768] unnormalized
    float2* __restrict__ ml){                 // [3][12][2304]
  __shared__ short KV[2][64*64];     // [0]=Ks [key][d-slots], [1]=Vs [d][key-slots]
  __shared__ short rlh_l[4][16][16]; // rel-h window for this part (bf16)
  __shared__ unsigned p_lds[4][16][32]; // P tile per wave: [q][key-pair dwords], swizzled

  short* Ks = KV[0];
  short* Vs = KV[1];
  short* rlt_sh = &KV[0][0];         // one-time overlay [4][16][66] bf16 (8448B)

  const int tid = threadIdx.x;
  const int w = tid >> 6, lane = tid & 63;
  const int head = blockIdx.y;
  const int part = blockIdx.z;
  const int n0 = blockIdx.x * 64;
  const int qbase = n0 + w*16;
  const int hq = qbase / 48;
  const int wq0 = qbase % 48;
  const int q = lane & 15, g = lane >> 4;

  // Q fragments (B-operand layout: col=q=lane&15, k=g*8+j), scaled by 1/8
  bf16x8 qf[2];
  {
    const __hip_bfloat16* qp = qkvb + (size_t)(qbase + q)*NTOK + head*64 + g*8;
    #pragma unroll
    for (int ks = 0; ks < 2; ++ks){
      bf16x8 t = *(const bf16x8*)(qp + 32*ks);
      #pragma unroll
      for (int j = 0; j < 8; ++j) t[j] = f2b(b2f(t[j]) * 0.125f);
      qf[ks] = t;
    }
  }

  // rel-h for the 16 hk rows this part touches (hk = part*16 + g*4 + r)
  {
    int grow = hq - (part*16 + q) + 47;
    f32x4 c = {};
    #pragma unroll
    for (int ks = 0; ks < 2; ++ks){
      bf16x8 a = *(const bf16x8*)(rphb + grow*64 + g*8 + 32*ks);
      c = MFMA16(a, qf[ks], c);
    }
    #pragma unroll
    for (int r = 0; r < 4; ++r) rlh_l[w][q][g*4 + r] = f2b(c[r] * 8.0f);
  }
  // rel-w table T[u][q] = q . Rw[wq0+62-u]  (u = wk - q + 15), one-time in overlay
  #pragma unroll
  for (int f = 0; f < 4; ++f){
    int grow = wq0 + 62 - (f*16 + q);
    if (grow < 0) grow = 0;
    f32x4 c = {};
    #pragma unroll
    for (int ks = 0; ks < 2; ++ks){
      bf16x8 a = *(const bf16x8*)(rpwb + grow*64 + g*8 + 32*ks);
      c = MFMA16(a, qf[ks], c);
    }
    #pragma unroll
    for (int r = 0; r < 4; ++r)
      rlt_sh[w*1056 + q*66 + f*16 + g*4 + r] = f2b(c[r] * 8.0f);
  }
  // hoist the only 12 rel-w values this lane ever needs into registers:
  // u(r,j) = (g*4+r) + 16*j - q + 15, j = (4*ci+kf)%3 selector in main loop
  float rlt_reg[4][3];
  #pragma unroll
  for (int r = 0; r < 4; ++r)
    #pragma unroll
    for (int j = 0; j < 3; ++j)
      rlt_reg[r][j] = b2f(rlt_sh[w*1056 + q*66 + (g*4+r) + 16*j - q + 15]);

  __syncthreads();   // all waves done with the rlt overlay before staging begins

  float m_run = -1e30f, l_run = 0.f;
  f32x4 oacc[4] = {};   // lane: O[qrow=g*4+r][d=df*16+q]

  const __hip_bfloat16* kgbase = qkvb + 768 + head*64;
  const __hip_bfloat16* vgbase = Vtg + (size_t)head*64*NTOK;
  char* prow = (char*)&p_lds[w][q][0];
  const int qs = q & 7;

  #pragma unroll
  for (int ci = 0; ci < 12; ++ci){
    const int ch = part*12 + ci;
    #pragma unroll
    for (int i = 0; i < 2; ++i){
      int e = i*256 + tid;
      int row = e >> 3, s = e & 7;
      int e0 = i*256 + w*64;
      GLOAD16(kgbase + (size_t)(ch*64 + row)*NTOK + (s ^ (row & 7))*8, (char*)Ks + e0*16);
      GLOAD16(vgbase + (size_t)row*NTOK + ch*64 + (s ^ (row & 7))*8,   (char*)Vs + e0*16);
    }
    __syncthreads();

    // St[key][q] = (Q*scale) . K   (key = kf*16 + q as A-row)
    f32x4 st[4];
    #pragma unroll
    for (int kf = 0; kf < 4; ++kf){
      int key = kf*16 + q;
      f32x4 c = {};
      #pragma unroll
      for (int ks = 0; ks < 2; ++ks){
        int slot = (4*ks + g) ^ qs;
        bf16x8 kf8 = *(const bf16x8*)((const char*)Ks + key*128 + slot*16);
        c = MFMA16(kf8, qf[ks], c);
      }
      st[kf] = c;
    }

    // add rel bias: per-kf constant hk, register rel-w (selector m compile-time)
    float sv[4][4];
    #pragma unroll
    for (int kf = 0; kf < 4; ++kf){
      const int m = (4*ci + kf) % 3;
      const int hloc = (4*ci + kf - m) / 3;
      float rh = b2f(rlh_l[w][q][hloc]);
      #pragma unroll
      for (int r = 0; r < 4; ++r)
        sv[kf][r] = st[kf][r] + rh + rlt_reg[r][m];
    }

    // online softmax over the 4-lane q-group, defer-max THR=8
    float cmax = -1e30f;
    #pragma unroll
    for (int kf = 0; kf < 4; ++kf)
      #pragma unroll
      for (int r = 0; r < 4; ++r) cmax = fmaxf(cmax, sv[kf][r]);
    cmax = fmaxf(cmax, __shfl_xor(cmax, 16));
    cmax = fmaxf(cmax, __shfl_xor(cmax, 32));
    float fs = 1.0f;
    if (__any(cmax > m_run + 8.0f)){
      float nm = fmaxf(m_run, cmax);
      fs = __expf(m_run - nm);
      m_run = nm;
      float fr[4];
      #pragma unroll
      for (int r = 0; r < 4; ++r) fr[r] = __shfl(fs, g*4 + r);
      #pragma unroll
      for (int df = 0; df < 4; ++df)
        #pragma unroll
        for (int r = 0; r < 4; ++r) oacc[df][r] *= fr[r];
    }
    float p[4][4]; float lsum = 0.f;
    #pragma unroll
    for (int kf = 0; kf < 4; ++kf)
      #pragma unroll
      for (int r = 0; r < 4; ++r){ p[kf][r] = __expf(sv[kf][r] - m_run); lsum += p[kf][r]; }
    lsum += __shfl_xor(lsum, 16);
    lsum += __shfl_xor(lsum, 32);
    l_run = l_run * fs + lsum;

    // P -> bf16 -> swizzled LDS (row q, key-pair dwords), then PV via b128 reads
    #pragma unroll
    for (int kf = 0; kf < 4; ++kf){
      unsigned lo = cvtpk(p[kf][0], p[kf][1]);
      unsigned hi = cvtpk(p[kf][2], p[kf][3]);
      *(uint2*)(prow + (((2*kf + (g>>1)) ^ qs) << 4) + ((g&1) << 3)) = make_uint2(lo, hi);
    }
    #pragma unroll
    for (int ks = 0; ks < 2; ++ks){
      bf16x8 pa = *(const bf16x8*)(prow + (((4*ks + g) ^ qs) << 4));
      #pragma unroll
      for (int df = 0; df < 4; ++df){
        int d = df*16 + q;
        int slot = (4*ks + g) ^ qs;
        bf16x8 vf8 = *(const bf16x8*)((const char*)Vs + d*128 + slot*16);
        oacc[df] = MFMA16(pa, vf8, oacc[df]);
      }
    }
    __syncthreads();
  }

  // write unnormalized partial O + (m,l) per q-row
  __hip_bfloat16* op = Opart + (size_t)part*NTOK*CDIM;
  #pragma unroll
  for (int df = 0; df < 4; ++df)
    #pragma unroll
    for (int r = 0; r < 4; ++r)
      op[(size_t)(qbase + g*4 + r)*CDIM + head*64 + df*16 + q] =
          __float2bfloat16(oacc[df][r]);
  if (g == 0)
    ml[(size_t)part*12*NTOK + head*NTOK + qbase + q] = make_float2(m_run, l_run);
}

// ------------- merge the 3 KV-split partials -------------
__global__ __launch_bounds__(256) void merge_attn(
    const __hip_bfloat16* __restrict__ Opart, const float2* __restrict__ ml,
    __hip_bfloat16* __restrict__ attb){
  const int n = blockIdx.x, tid = threadIdx.x;
  #pragma unroll
  for (int j = 0; j < 3; ++j){
    int c = tid + j*256;
    int h = c >> 6;
    float2 a = ml[h*NTOK + n];
    float2 b = ml[12*NTOK + h*NTOK + n];
    float2 d = ml[2*12*NTOK + h*NTOK + n];
    float M = fmaxf(a.x, fmaxf(b.x, d.x));
    float e0 = __expf(a.x - M), e1 = __expf(b.x - M), e2 = __expf(d.x - M);
    float L = a.y*e0 + b.y*e1 + d.y*e2;
    float o0 = __bfloat162float(Opart[(size_t)n*CDIM + c]);
    float o1 = __bfloat162float(Opart[(size_t)NTOK*CDIM + n*CDIM + c]);
    float o2 = __bfloat162float(Opart[(size_t)2*NTOK*CDIM + n*CDIM + c]);
    attb[(size_t)n*CDIM + c] = __float2bfloat16((o0*e0 + o1*e1 + o2*e2) / L);
  }
}

// ------------- proj split-K merge + residual + LN2 fused -------------
__global__ __launch_bounds__(256) void merge_proj_ln(
    const float* __restrict__ x, const float* __restrict__ Cp,
    const float* __restrict__ pb,
    const float* __restrict__ g2, const float* __restrict__ b2,
    __hip_bfloat16* __restrict__ x1b, __hip_bfloat16* __restrict__ yb){
  __shared__ float sm[4];
  const int row = blockIdx.x, tid = threadIdx.x;
  float v[3];
  #pragma unroll
  for (int j = 0; j < 3; ++j){
    int c = tid + j*256;
    size_t o = (size_t)row*CDIM + c;
    float s = x[o] + pb[c];
    s += Cp[o] + Cp[(size_t)NTOK*CDIM + o] + Cp[(size_t)2*NTOK*CDIM + o];
    v[j] = s;
    x1b[o] = __float2bfloat16(s);
  }
  float s = wsum(v[0]+v[1]+v[2]);
  if ((tid & 63)==0) sm[tid>>6] = s;
  __syncthreads();
  float mean = (sm[0]+sm[1]+sm[2]+sm[3]) * (1.0f/CDIM);
  __syncthreads();
  float d0=v[0]-mean, d1=v[1]-mean, d2=v[2]-mean;
  float ss = wsum(d0*d0+d1*d1+d2*d2);
  if ((tid&63)==0) sm[tid>>6] = ss;
  __syncthreads();
  float rstd = rsqrtf((sm[0]+sm[1]+sm[2]+sm[3])*(1.0f/CDIM) + 1e-6f);
  __hip_bfloat16* o = yb + (size_t)row*CDIM;
  o[tid]     = __float2bfloat16(d0*rstd*g2[tid]     + b2[tid]);
  o[tid+256] = __float2bfloat16(d1*rstd*g2[tid+256] + b2[tid+256]);
  o[tid+512] = __float2bfloat16(d2*rstd*g2[tid+512] + b2[tid+512]);
}

// ------------- mlp2 split-K merge + residual -> f32 out -------------
__global__ __launch_bounds__(256) void merge_mlp2(
    const __hip_bfloat16* __restrict__ x1b, const float* __restrict__ Cp,
    const float* __restrict__ bias, float* __restrict__ out){
  const int row = blockIdx.x, tid = threadIdx.x;
  #pragma unroll
  for (int j = 0; j < 3; ++j){
    int c = tid + j*256;
    size_t o = (size_t)row*CDIM + c;
    float s = __bfloat162float(x1b[o]) + bias[c];
    s += Cp[o] + Cp[(size_t)NTOK*CDIM + o] + Cp[(size_t)2*NTOK*CDIM + o];
    out[o] = s;
  }
}

extern "C" void kernel_launch(void* const* d_in, const int* in_sizes, int n_in,
                              void* d_out, int out_size, void* d_ws, size_t ws_size,
                              hipStream_t stream) {
  const float* x      = (const float*)d_in[0];
  const float* ln1_g  = (const float*)d_in[1];
  const float* ln1_b  = (const float*)d_in[2];
  const float* qkv_w  = (const float*)d_in[3];
  const float* qkv_b  = (const float*)d_in[4];
  const float* rph    = (const float*)d_in[5];
  const float* rpw    = (const float*)d_in[6];
  const float* proj_w = (const float*)d_in[7];
  const float* proj_b = (const float*)d_in[8];
  const float* ln2_g  = (const float*)d_in[9];
  const float* ln2_b  = (const float*)d_in[10];
  const float* mlp_w1 = (const float*)d_in[11];
  const float* mlp_b1 = (const float*)d_in[12];
  const float* mlp_w2 = (const float*)d_in[13];
  const float* mlp_b2 = (const float*)d_in[14];

  char* ws = (char*)d_ws;
  // layout (bytes), lifetime-checked:
  __hip_bfloat16* x1b   = (__hip_bfloat16*)(ws);              // [0, 3.54M)
  __hip_bfloat16* m2T   = (__hip_bfloat16*)(ws + 3538944);    // [3.54M, 8.26M)
  __hip_bfloat16* hb    = (__hip_bfloat16*)(ws + 8257536);    // [8.26M, 22.41M) (mlp1 out)
  __hip_bfloat16* qkvb  = (__hip_bfloat16*)(ws + 8257536);    // [8.26M, 18.87M) dead after attn
  __hip_bfloat16* Opart = (__hip_bfloat16*)(ws + 18874368);   // [18.87M, 29.49M)
  float*          Cpp   = (float*)         (ws + 8257536);    // proj partials [8.26M, 29.49M)
  float*          Cpm   = (float*)         (ws + 22413312);   // mlp2 partials [22.41M, 43.65M)
  float2*         mlbuf = (float2*)        (ws + 29491200);   // [29.49M, 30.15M)
  __hip_bfloat16* Vtg   = (__hip_bfloat16*)(ws + 30154752);   // [30.15M, 33.69M)
  __hip_bfloat16* qkvT  = (__hip_bfloat16*)(ws + 33693696);   // [33.69M, 37.23M)
  __hip_bfloat16* attb  = (__hip_bfloat16*)(ws + 33693696);   // alias, after qkv gemm
  __hip_bfloat16* projT = (__hip_bfloat16*)(ws + 37232640);   // [37.23M, 38.41M)
  __hip_bfloat16* m1T   = (__hip_bfloat16*)(ws + 38412288);   // [38.41M, 43.13M)
  __hip_bfloat16* rphb  = (__hip_bfloat16*)(ws + 43646976);
  __hip_bfloat16* rpwb  = (__hip_bfloat16*)(ws + 43659136);
  __hip_bfloat16* yb    = (__hip_bfloat16*)(ws + 43671296);   // [43.67M, 47.21M) ln1/ln2 out

  prep_kernel<<<6936, 256, 0, stream>>>(qkv_w, proj_w, mlp_w1, mlp_w2, rph, rpw,
                                        qkvT, projT, m1T, m2T, rphb, rpwb);
  ln_kernel<<<NTOK, 256, 0, stream>>>(x, ln1_g, ln1_b, yb);

  // qkv = xn @ qkv_w + b   (2304 x 768 x 2304)
  gemm_bf16<0,0><<<dim3(18, 18), 256, 0, stream>>>(
      yb, qkvT, qkv_b, qkvb, NTOK, 768, 2304, 24);

  vt_kernel<<<dim3(72, 2, 12), 256, 0, stream>>>(qkvb, Vtg);
  attn_mfma<<<dim3(36, 12, 3), 256, 0, stream>>>(qkvb, Vtg, rphb, rpwb, Opart, mlbuf);
  merge_attn<<<NTOK, 256, 0, stream>>>(Opart, mlbuf, attb);

  // proj partials (2304 x 768 x 768), split-K=3
  gemm_bf16<0,1><<<dim3(6, 18, 3), 256, 0, stream>>>(
      attb, projT, nullptr, Cpp, NTOK, 768, 768, 8);
  merge_proj_ln<<<NTOK, 256, 0, stream>>>(x, Cpp, proj_b, ln2_g, ln2_b, x1b, yb);

  // h = gelu(y @ mlp_w1 + b)   (2304 x 768 x 3072)
  gemm_bf16<1,0><<<dim3(24, 18), 256, 0, stream>>>(
      yb, m1T, mlp_b1, hb, NTOK, 768, 3072, 24);

  // mlp2 partials (2304 x 3072 x 768), split-K=3
  gemm_bf16<0,1><<<dim3(6, 18, 3), 256, 0, stream>>>(
      hb, m2T, nullptr, Cpm, NTOK, 3072, 768, 32);
  merge_mlp2<<<NTOK, 256, 0, stream>>>(x1b, Cpm, mlp_b2, (float*)d_out);
}

// Round 8
// 255.326 us; speedup vs baseline: 8.2965x; 1.0357x over previous
//
#include <hip/hip_runtime.h>
#include <hip/hip_bf16.h>
#include <math.h>

#define NTOK 2304
#define CDIM 768

typedef __attribute__((ext_vector_type(8))) short bf16x8;
typedef __attribute__((ext_vector_type(4))) float f32x4;

#define MFMA16(a,b,c) __builtin_amdgcn_mfma_f32_16x16x32_bf16(a,b,c,0,0,0)
#define GLOAD16(g, l) __builtin_amdgcn_global_load_lds( \
    (const __attribute__((address_space(1))) void*)(g), \
    (__attribute__((address_space(3))) void*)(l), 16, 0, 0)

__device__ __forceinline__ short f2b(float f){
  __hip_bfloat16 h = __float2bfloat16(f);
  short s; __builtin_memcpy(&s, &h, 2); return s;
}
__device__ __forceinline__ float b2f(short s){
  __hip_bfloat16 h; __builtin_memcpy(&h, &s, 2); return __bfloat162float(h);
}
__device__ __forceinline__ unsigned cvtpk(float a, float b){
  unsigned r;
  asm("v_cvt_pk_bf16_f32 %0, %1, %2" : "=v"(r) : "v"(a), "v"(b));
  return r;
}
__device__ __forceinline__ float wsum(float v){
  #pragma unroll
  for (int o = 32; o > 0; o >>= 1) v += __shfl_xor(v, o);
  return v;
}

// ---------------- fused prep: 4x weight transpose+cast + relpos cast + LN1 ----
__device__ __forceinline__ void wt_tile(const float* __restrict__ W,
    __hip_bfloat16* __restrict__ Wt, int K, int N, int tx, int ty,
    float (*t)[33], int tid){
  const int n0 = tx*32, k0 = ty*32;
  const int c = tid & 31, r0 = tid >> 5;
  #pragma unroll
  for (int i = 0; i < 4; ++i){
    int r = r0 + i*8;
    t[r][c] = W[(size_t)(k0 + r)*N + n0 + c];
  }
  __syncthreads();
  #pragma unroll
  for (int i = 0; i < 4; ++i){
    int r = r0 + i*8;
    Wt[(size_t)(n0 + r)*K + k0 + c] = __float2bfloat16(t[c][r]);
  }
}

__device__ __forceinline__ void ln_row(const float* __restrict__ xr,
    const float* __restrict__ g, const float* __restrict__ b,
    __hip_bfloat16* __restrict__ o, float* sm, int tid){
  float v0 = xr[tid], v1 = xr[tid+256], v2 = xr[tid+512];
  float s = wsum(v0+v1+v2);
  if ((tid & 63)==0) sm[tid>>6] = s;
  __syncthreads();
  float mean = (sm[0]+sm[1]+sm[2]+sm[3]) * (1.0f/CDIM);
  __syncthreads();
  float d0=v0-mean, d1=v1-mean, d2=v2-mean;
  float ss = wsum(d0*d0+d1*d1+d2*d2);
  if ((tid&63)==0) sm[tid>>6] = ss;
  __syncthreads();
  float rstd = rsqrtf((sm[0]+sm[1]+sm[2]+sm[3])*(1.0f/CDIM) + 1e-6f);
  o[tid]     = __float2bfloat16(d0*rstd*g[tid]     + b[tid]);
  o[tid+256] = __float2bfloat16(d1*rstd*g[tid+256] + b[tid+256]);
  o[tid+512] = __float2bfloat16(d2*rstd*g[tid+512] + b[tid+512]);
}

__global__ __launch_bounds__(256) void prep_kernel(
    const float* __restrict__ qkv_w, const float* __restrict__ proj_w,
    const float* __restrict__ m1w, const float* __restrict__ m2w,
    const float* __restrict__ rph, const float* __restrict__ rpw,
    const float* __restrict__ x, const float* __restrict__ ln1_g,
    const float* __restrict__ ln1_b,
    __hip_bfloat16* __restrict__ qkvT, __hip_bfloat16* __restrict__ projT,
    __hip_bfloat16* __restrict__ m1T, __hip_bfloat16* __restrict__ m2T,
    __hip_bfloat16* __restrict__ rphb, __hip_bfloat16* __restrict__ rpwb,
    __hip_bfloat16* __restrict__ yb){
  __shared__ float t[32][33];
  __shared__ float sm[4];
  int id = blockIdx.x, tid = threadIdx.x;
  if (id < 1728)      wt_tile(qkv_w, qkvT, 768, 2304, id%72, id/72, t, tid);
  else if (id < 2304){ id -= 1728; wt_tile(proj_w, projT, 768, 768, id%24, id/24, t, tid); }
  else if (id < 4608){ id -= 2304; wt_tile(m1w, m1T, 768, 3072, id%96, id/96, t, tid); }
  else if (id < 6912){ id -= 4608; wt_tile(m2w, m2T, 3072, 768, id%24, id/24, t, tid); }
  else if (id < 6936){
    int i = (id - 6912)*256 + tid;
    if (i < 95*64){ rphb[i] = __float2bfloat16(rph[i]); rpwb[i] = __float2bfloat16(rpw[i]); }
  } else {
    int row = id - 6936;
    ln_row(x + (size_t)row*CDIM, ln1_g, ln1_b, yb + (size_t)row*CDIM, sm, tid);
  }
}

// ------------- V transpose: qkvb[n][1536+h*64+d] -> Vtg[h][d][n] -------------
__global__ __launch_bounds__(256) void vt_kernel(const __hip_bfloat16* __restrict__ qkvb,
    __hip_bfloat16* __restrict__ Vtg){
  __shared__ __hip_bfloat16 t[32][33];
  const int n0 = blockIdx.x*32, d0 = blockIdx.y*32, h = blockIdx.z;
  const int c = threadIdx.x & 31, r0 = threadIdx.x >> 5;
  #pragma unroll
  for (int i = 0; i < 4; ++i){
    int r = r0 + i*8;
    t[r][c] = qkvb[(size_t)(n0+r)*NTOK + 1536 + h*64 + d0 + c];
  }
  __syncthreads();
  #pragma unroll
  for (int i = 0; i < 4; ++i){
    int r = r0 + i*8;
    Vtg[((size_t)h*64 + d0 + r)*NTOK + n0 + c] = t[c][r];
  }
}

// ------------- bf16 MFMA GEMM, 128x64 tile, 2-phase prefetch, opt split-K ----
// PARTIAL=0: C=bf16(A@Bt^T + bias [gelu]); PARTIAL=1: f32 partial (no bias).
template<int ACT, int PARTIAL>
__global__ __launch_bounds__(256) void gemm_bf16(
    const __hip_bfloat16* __restrict__ A, const __hip_bfloat16* __restrict__ Bt,
    const float* __restrict__ bias, void* __restrict__ Cout,
    int M, int K, int N, int kst){
  __shared__ short As[2][128*32];
  __shared__ short Bs[2][64*32];
  const int tid = threadIdx.x;
  const int w = tid >> 6, lane = tid & 63;
  const int wr = w >> 1, wc = w & 1;
  const int bm = blockIdx.y*128, bn = blockIdx.x*64;
  const int kbase = blockIdx.z * kst * 32;
  const int l15 = lane & 15, l4 = lane >> 4;
  f32x4 acc[4][2] = {};

  const int ra = wr*64 + l15;          // wave M-tile 64
  const int rb = wc*32 + l15;          // wave N-tile 32
  const int kswa = l4 ^ ((ra>>1)&3);
  const int kswb = l4 ^ ((rb>>1)&3);

  auto STAGE = [&](int buf, int k0){
    #pragma unroll
    for (int r = 0; r < 3; ++r){
      if (r < 2){
        int e = r*256 + tid;
        int row = e >> 2, s = e & 3, gs = s ^ ((row>>1)&3);
        GLOAD16(A + (size_t)(bm+row)*K + k0 + gs*8, (char*)As[buf] + ((r*256 + w*64)<<4));
      } else {
        int e = tid;
        int row = e >> 2, s = e & 3, gs = s ^ ((row>>1)&3);
        GLOAD16(Bt + (size_t)(bn+row)*K + k0 + gs*8, (char*)Bs[buf] + ((w*64)<<4));
      }
    }
  };

  STAGE(0, kbase);
  __syncthreads();
  int cur = 0;
  for (int t = 0; t < kst; ++t){
    if (t+1 < kst) STAGE(cur^1, kbase + (t+1)*32);
    bf16x8 af[4], bfr[2];
    #pragma unroll
    for (int m = 0; m < 4; ++m)
      af[m] = *(const bf16x8*)((const char*)As[cur] + (ra + m*16)*64 + kswa*16);
    #pragma unroll
    for (int n = 0; n < 2; ++n)
      bfr[n] = *(const bf16x8*)((const char*)Bs[cur] + (rb + n*16)*64 + kswb*16);
    #pragma unroll
    for (int m = 0; m < 4; ++m)
      #pragma unroll
      for (int n = 0; n < 2; ++n)
        acc[m][n] = MFMA16(af[m], bfr[n], acc[m][n]);
    __syncthreads();
    cur ^= 1;
  }

  const int crow = bm + wr*64 + l4*4;
  const int ccol = bn + wc*32 + l15;
  float* Cp = (float*)Cout + (size_t)blockIdx.z*M*N;
  #pragma unroll
  for (int m = 0; m < 4; ++m){
    #pragma unroll
    for (int n = 0; n < 2; ++n){
      #pragma unroll
      for (int r = 0; r < 4; ++r){
        int rr = crow + m*16 + r, cc = ccol + n*16;
        if (PARTIAL){
          Cp[(size_t)rr*N + cc] = acc[m][n][r];
        } else {
          float v = acc[m][n][r] + bias[cc];
          if (ACT == 1) v = 0.5f * v * (1.0f + erff(v * 0.70710678118654752f));
          ((__hip_bfloat16*)Cout)[(size_t)rr*N + cc] = __float2bfloat16(v);
        }
      }
    }
  }
}

// ------------- MFMA flash attention, KV-split x3, double-buffered staging ----
// grid (36, 12, 3): 64 queries/block (4 waves x 16q), part z does chunks [12z,12z+12)
__global__ __launch_bounds__(256) void attn_mfma(
    const __hip_bfloat16* __restrict__ qkvb,  // [2304][2304]
    const __hip_bfloat16* __restrict__ Vtg,   // [12][64][2304]
    const __hip_bfloat16* __restrict__ rphb,  // [95][64]
    const __hip_bfloat16* __restrict__ rpwb,  // [95][64]
    __hip_bfloat16* __restrict__ Opart,       // [3][2304][768] unnormalized
    float2* __restrict__ ml){                 // [3][12][2304]
  __shared__ short KVbuf[4][64*64];  // [b]=Ks buf b, [2+b]=Vs buf b (dbuf)
  __shared__ short rlh_l[4][16][16]; // rel-h window for this part (bf16)
  __shared__ unsigned p_lds[4][16][32]; // P tile per wave, swizzled

  short* rlt_sh = &KVbuf[0][0];      // one-time overlay [4][16][66] bf16 (8448B)

  const int tid = threadIdx.x;
  const int w = tid >> 6, lane = tid & 63;
  const int head = blockIdx.y;
  const int part = blockIdx.z;
  const int n0 = blockIdx.x * 64;
  const int qbase = n0 + w*16;
  const int hq = qbase / 48;
  const int wq0 = qbase % 48;
  const int q = lane & 15, g = lane >> 4;

  // Q fragments (B-operand layout: col=q=lane&15, k=g*8+j), scaled by 1/8
  bf16x8 qf[2];
  {
    const __hip_bfloat16* qp = qkvb + (size_t)(qbase + q)*NTOK + head*64 + g*8;
    #pragma unroll
    for (int ks = 0; ks < 2; ++ks){
      bf16x8 t = *(const bf16x8*)(qp + 32*ks);
      #pragma unroll
      for (int j = 0; j < 8; ++j) t[j] = f2b(b2f(t[j]) * 0.125f);
      qf[ks] = t;
    }
  }

  // rel-h for the 16 hk rows this part touches (hk = part*16 + g*4 + r)
  {
    int grow = hq - (part*16 + q) + 47;
    f32x4 c = {};
    #pragma unroll
    for (int ks = 0; ks < 2; ++ks){
      bf16x8 a = *(const bf16x8*)(rphb + grow*64 + g*8 + 32*ks);
      c = MFMA16(a, qf[ks], c);
    }
    #pragma unroll
    for (int r = 0; r < 4; ++r) rlh_l[w][q][g*4 + r] = f2b(c[r] * 8.0f);
  }
  // rel-w table T[u][q] = q . Rw[wq0+62-u]  (u = wk - q + 15), one-time overlay
  #pragma unroll
  for (int f = 0; f < 4; ++f){
    int grow = wq0 + 62 - (f*16 + q);
    if (grow < 0) grow = 0;
    f32x4 c = {};
    #pragma unroll
    for (int ks = 0; ks < 2; ++ks){
      bf16x8 a = *(const bf16x8*)(rpwb + grow*64 + g*8 + 32*ks);
      c = MFMA16(a, qf[ks], c);
    }
    #pragma unroll
    for (int r = 0; r < 4; ++r)
      rlt_sh[w*1056 + q*66 + f*16 + g*4 + r] = f2b(c[r] * 8.0f);
  }
  // hoist the 12 rel-w values this lane needs into registers:
  // u(r,j) = (g*4+r) + 16*j - q + 15, j = (4*ci+kf)%3 selector in main loop
  float rlt_reg[4][3];
  #pragma unroll
  for (int r = 0; r < 4; ++r)
    #pragma unroll
    for (int j = 0; j < 3; ++j)
      rlt_reg[r][j] = b2f(rlt_sh[w*1056 + q*66 + (g*4+r) + 16*j - q + 15]);

  __syncthreads();   // all waves done with the rlt overlay before staging begins

  float m_run = -1e30f, l_run = 0.f;
  f32x4 oacc[4] = {};   // lane: O[qrow=g*4+r][d=df*16+q]

  const __hip_bfloat16* kgbase = qkvb + 768 + head*64;
  const __hip_bfloat16* vgbase = Vtg + (size_t)head*64*NTOK;
  char* prow = (char*)&p_lds[w][q][0];
  const int qs = q & 7;

  auto STAGE_KV = [&](int buf, int ch){
    #pragma unroll
    for (int i = 0; i < 2; ++i){
      int e = i*256 + tid;
      int row = e >> 3, s = e & 7;
      int e0 = i*256 + w*64;
      GLOAD16(kgbase + (size_t)(ch*64 + row)*NTOK + (s ^ (row & 7))*8,
              (char*)KVbuf[buf] + e0*16);
      GLOAD16(vgbase + (size_t)row*NTOK + ch*64 + (s ^ (row & 7))*8,
              (char*)KVbuf[2+buf] + e0*16);
    }
  };

  STAGE_KV(0, part*12);          // prologue
  int cur = 0;
  #pragma unroll
  for (int ci = 0; ci < 12; ++ci){
    __syncthreads();             // drains cur's loads; separates buffer reuse
    if (ci+1 < 12) STAGE_KV(cur^1, part*12 + ci + 1);  // overlap next with compute
    const short* Ks = KVbuf[cur];
    const short* Vs = KVbuf[2+cur];

    // St[key][q] = (Q*scale) . K   (key = kf*16 + q as A-row)
    f32x4 st[4];
    #pragma unroll
    for (int kf = 0; kf < 4; ++kf){
      int key = kf*16 + q;
      f32x4 c = {};
      #pragma unroll
      for (int ks = 0; ks < 2; ++ks){
        int slot = (4*ks + g) ^ qs;
        bf16x8 kf8 = *(const bf16x8*)((const char*)Ks + key*128 + slot*16);
        c = MFMA16(kf8, qf[ks], c);
      }
      st[kf] = c;
    }

    // add rel bias: per-kf constant hk, register rel-w (selector compile-time)
    float sv[4][4];
    #pragma unroll
    for (int kf = 0; kf < 4; ++kf){
      const int m = (4*ci + kf) % 3;
      const int hloc = (4*ci + kf - m) / 3;
      float rh = b2f(rlh_l[w][q][hloc]);
      #pragma unroll
      for (int r = 0; r < 4; ++r)
        sv[kf][r] = st[kf][r] + rh + rlt_reg[r][m];
    }

    // online softmax over the 4-lane q-group, defer-max THR=8
    float cmax = -1e30f;
    #pragma unroll
    for (int kf = 0; kf < 4; ++kf)
      #pragma unroll
      for (int r = 0; r < 4; ++r) cmax = fmaxf(cmax, sv[kf][r]);
    cmax = fmaxf(cmax, __shfl_xor(cmax, 16));
    cmax = fmaxf(cmax, __shfl_xor(cmax, 32));
    float fs = 1.0f;
    if (__any(cmax > m_run + 8.0f)){
      float nm = fmaxf(m_run, cmax);
      fs = __expf(m_run - nm);
      m_run = nm;
      float fr[4];
      #pragma unroll
      for (int r = 0; r < 4; ++r) fr[r] = __shfl(fs, g*4 + r);
      #pragma unroll
      for (int df = 0; df < 4; ++df)
        #pragma unroll
        for (int r = 0; r < 4; ++r) oacc[df][r] *= fr[r];
    }
    float p[4][4]; float lsum = 0.f;
    #pragma unroll
    for (int kf = 0; kf < 4; ++kf)
      #pragma unroll
      for (int r = 0; r < 4; ++r){ p[kf][r] = __expf(sv[kf][r] - m_run); lsum += p[kf][r]; }
    lsum += __shfl_xor(lsum, 16);
    lsum += __shfl_xor(lsum, 32);
    l_run = l_run * fs + lsum;

    // P -> bf16 -> swizzled LDS (wave-private), then PV via b128 reads
    #pragma unroll
    for (int kf = 0; kf < 4; ++kf){
      unsigned lo = cvtpk(p[kf][0], p[kf][1]);
      unsigned hi = cvtpk(p[kf][2], p[kf][3]);
      *(uint2*)(prow + (((2*kf + (g>>1)) ^ qs) << 4) + ((g&1) << 3)) = make_uint2(lo, hi);
    }
    #pragma unroll
    for (int ks = 0; ks < 2; ++ks){
      bf16x8 pa = *(const bf16x8*)(prow + (((4*ks + g) ^ qs) << 4));
      #pragma unroll
      for (int df = 0; df < 4; ++df){
        int d = df*16 + q;
        int slot = (4*ks + g) ^ qs;
        bf16x8 vf8 = *(const bf16x8*)((const char*)Vs + d*128 + slot*16);
        oacc[df] = MFMA16(pa, vf8, oacc[df]);
      }
    }
    cur ^= 1;
  }

  // write unnormalized partial O + (m,l) per q-row
  __hip_bfloat16* op = Opart + (size_t)part*NTOK*CDIM;
  #pragma unroll
  for (int df = 0; df < 4; ++df)
    #pragma unroll
    for (int r = 0; r < 4; ++r)
      op[(size_t)(qbase + g*4 + r)*CDIM + head*64 + df*16 + q] =
          __float2bfloat16(oacc[df][r]);
  if (g == 0)
    ml[(size_t)part*12*NTOK + head*NTOK + qbase + q] = make_float2(m_run, l_run);
}

// ------------- merge the 3 KV-split partials -------------
__global__ __launch_bounds__(256) void merge_attn(
    const __hip_bfloat16* __restrict__ Opart, const float2* __restrict__ ml,
    __hip_bfloat16* __restrict__ attb){
  const int n = blockIdx.x, tid = threadIdx.x;
  #pragma unroll
  for (int j = 0; j < 3; ++j){
    int c = tid + j*256;
    int h = c >> 6;
    float2 a = ml[h*NTOK + n];
    float2 b = ml[12*NTOK + h*NTOK + n];
    float2 d = ml[2*12*NTOK + h*NTOK + n];
    float M = fmaxf(a.x, fmaxf(b.x, d.x));
    float e0 = __expf(a.x - M), e1 = __expf(b.x - M), e2 = __expf(d.x - M);
    float L = a.y*e0 + b.y*e1 + d.y*e2;
    float o0 = __bfloat162float(Opart[(size_t)n*CDIM + c]);
    float o1 = __bfloat162float(Opart[(size_t)NTOK*CDIM + n*CDIM + c]);
    float o2 = __bfloat162float(Opart[(size_t)2*NTOK*CDIM + n*CDIM + c]);
    attb[(size_t)n*CDIM + c] = __float2bfloat16((o0*e0 + o1*e1 + o2*e2) / L);
  }
}

// ------------- proj split-K(2) merge + residual + LN2 fused -------------
__global__ __launch_bounds__(256) void merge_proj_ln(
    const float* __restrict__ x, const float* __restrict__ Cp,
    const float* __restrict__ pb,
    const float* __restrict__ g2, const float* __restrict__ b2,
    __hip_bfloat16* __restrict__ x1b, __hip_bfloat16* __restrict__ yb){
  __shared__ float sm[4];
  const int row = blockIdx.x, tid = threadIdx.x;
  float v[3];
  #pragma unroll
  for (int j = 0; j < 3; ++j){
    int c = tid + j*256;
    size_t o = (size_t)row*CDIM + c;
    float s = x[o] + pb[c];
    s += Cp[o] + Cp[(size_t)NTOK*CDIM + o];
    v[j] = s;
    x1b[o] = __float2bfloat16(s);
  }
  float s = wsum(v[0]+v[1]+v[2]);
  if ((tid & 63)==0) sm[tid>>6] = s;
  __syncthreads();
  float mean = (sm[0]+sm[1]+sm[2]+sm[3]) * (1.0f/CDIM);
  __syncthreads();
  float d0=v[0]-mean, d1=v[1]-mean, d2=v[2]-mean;
  float ss = wsum(d0*d0+d1*d1+d2*d2);
  if ((tid&63)==0) sm[tid>>6] = ss;
  __syncthreads();
  float rstd = rsqrtf((sm[0]+sm[1]+sm[2]+sm[3])*(1.0f/CDIM) + 1e-6f);
  __hip_bfloat16* o = yb + (size_t)row*CDIM;
  o[tid]     = __float2bfloat16(d0*rstd*g2[tid]     + b2[tid]);
  o[tid+256] = __float2bfloat16(d1*rstd*g2[tid+256] + b2[tid+256]);
  o[tid+512] = __float2bfloat16(d2*rstd*g2[tid+512] + b2[tid+512]);
}

// ------------- mlp2 split-K(3) merge + residual -> f32 out -------------
__global__ __launch_bounds__(256) void merge_mlp2(
    const __hip_bfloat16* __restrict__ x1b, const float* __restrict__ Cp,
    const float* __restrict__ bias, float* __restrict__ out){
  const int row = blockIdx.x, tid = threadIdx.x;
  #pragma unroll
  for (int j = 0; j < 3; ++j){
    int c = tid + j*256;
    size_t o = (size_t)row*CDIM + c;
    float s = __bfloat162float(x1b[o]) + bias[c];
    s += Cp[o] + Cp[(size_t)NTOK*CDIM + o] + Cp[(size_t)2*NTOK*CDIM + o];
    out[o] = s;
  }
}

extern "C" void kernel_launch(void* const* d_in, const int* in_sizes, int n_in,
                              void* d_out, int out_size, void* d_ws, size_t ws_size,
                              hipStream_t stream) {
  const float* x      = (const float*)d_in[0];
  const float* ln1_g  = (const float*)d_in[1];
  const float* ln1_b  = (const float*)d_in[2];
  const float* qkv_w  = (const float*)d_in[3];
  const float* qkv_b  = (const float*)d_in[4];
  const float* rph    = (const float*)d_in[5];
  const float* rpw    = (const float*)d_in[6];
  const float* proj_w = (const float*)d_in[7];
  const float* proj_b = (const float*)d_in[8];
  const float* ln2_g  = (const float*)d_in[9];
  const float* ln2_b  = (const float*)d_in[10];
  const float* mlp_w1 = (const float*)d_in[11];
  const float* mlp_b1 = (const float*)d_in[12];
  const float* mlp_w2 = (const float*)d_in[13];
  const float* mlp_b2 = (const float*)d_in[14];

  char* ws = (char*)d_ws;
  // layout (bytes), lifetime-checked:
  __hip_bfloat16* x1b   = (__hip_bfloat16*)(ws);              // [0, 3.54M)
  __hip_bfloat16* m2T   = (__hip_bfloat16*)(ws + 3538944);    // [3.54M, 8.26M)
  __hip_bfloat16* hb    = (__hip_bfloat16*)(ws + 8257536);    // [8.26M, 22.41M) (mlp1 out)
  __hip_bfloat16* qkvb  = (__hip_bfloat16*)(ws + 8257536);    // [8.26M, 18.87M) dead after attn
  __hip_bfloat16* Opart = (__hip_bfloat16*)(ws + 18874368);   // [18.87M, 29.49M)
  float*          Cpp   = (float*)         (ws + 8257536);    // proj partials x2 [8.26M, 22.41M)
  float*          Cpm   = (float*)         (ws + 22413312);   // mlp2 partials x3 [22.41M, 43.65M)
  float2*         mlbuf = (float2*)        (ws + 29491200);   // [29.49M, 30.15M)
  __hip_bfloat16* Vtg   = (__hip_bfloat16*)(ws + 30154752);   // [30.15M, 33.69M)
  __hip_bfloat16* qkvT  = (__hip_bfloat16*)(ws + 33693696);   // [33.69M, 37.23M)
  __hip_bfloat16* attb  = (__hip_bfloat16*)(ws + 33693696);   // alias, after qkv gemm
  __hip_bfloat16* projT = (__hip_bfloat16*)(ws + 37232640);   // [37.23M, 38.41M)
  __hip_bfloat16* m1T   = (__hip_bfloat16*)(ws + 38412288);   // [38.41M, 43.13M)
  __hip_bfloat16* rphb  = (__hip_bfloat16*)(ws + 43646976);
  __hip_bfloat16* rpwb  = (__hip_bfloat16*)(ws + 43659136);
  __hip_bfloat16* yb    = (__hip_bfloat16*)(ws + 43671296);   // [43.67M, 47.21M) ln out

  // prep: weight transposes + relpos cast + LN1 (ids 6936..9239)
  prep_kernel<<<9240, 256, 0, stream>>>(qkv_w, proj_w, mlp_w1, mlp_w2, rph, rpw,
                                        x, ln1_g, ln1_b,
                                        qkvT, projT, m1T, m2T, rphb, rpwb, yb);

  // qkv = xn @ qkv_w + b   (2304 x 768 x 2304), 128x64 tiles -> 648 blocks
  gemm_bf16<0,0><<<dim3(36, 18), 256, 0, stream>>>(
      yb, qkvT, qkv_b, qkvb, NTOK, 768, 2304, 24);

  vt_kernel<<<dim3(72, 2, 12), 256, 0, stream>>>(qkvb, Vtg);
  attn_mfma<<<dim3(36, 12, 3), 256, 0, stream>>>(qkvb, Vtg, rphb, rpwb, Opart, mlbuf);
  merge_attn<<<NTOK, 256, 0, stream>>>(Opart, mlbuf, attb);

  // proj partials (2304 x 768 x 768), split-K=2 -> 432 blocks
  gemm_bf16<0,1><<<dim3(12, 18, 2), 256, 0, stream>>>(
      attb, projT, nullptr, Cpp, NTOK, 768, 768, 12);
  merge_proj_ln<<<NTOK, 256, 0, stream>>>(x, Cpp, proj_b, ln2_g, ln2_b, x1b, yb);

  // h = gelu(y @ mlp_w1 + b)   (2304 x 768 x 3072) -> 864 blocks
  gemm_bf16<1,0><<<dim3(48, 18), 256, 0, stream>>>(
      yb, m1T, mlp_b1, hb, NTOK, 768, 3072, 24);

  // mlp2 partials (2304 x 3072 x 768), split-K=3 -> 648 blocks
  gemm_bf16<0,1><<<dim3(12, 18, 3), 256, 0, stream>>>(
      hb, m2T, nullptr, Cpm, NTOK, 3072, 768, 32);
  merge_mlp2<<<NTOK, 256, 0, stream>>>(x1b, Cpm, mlp_b2, (float*)d_out);
}

// Round 13
// 254.089 us; speedup vs baseline: 8.3369x; 1.0049x over previous
//
#include <hip/hip_runtime.h>
#include <hip/hip_bf16.h>
#include <math.h>

#define NTOK 2304
#define CDIM 768

typedef __attribute__((ext_vector_type(8))) short bf16x8;
typedef __attribute__((ext_vector_type(4))) float f32x4;

#define MFMA16(a,b,c) __builtin_amdgcn_mfma_f32_16x16x32_bf16(a,b,c,0,0,0)
#define GLOAD16(g, l) __builtin_amdgcn_global_load_lds( \
    (const __attribute__((address_space(1))) void*)(g), \
    (__attribute__((address_space(3))) void*)(l), 16, 0, 0)

__device__ __forceinline__ short f2b(float f){
  __hip_bfloat16 h = __float2bfloat16(f);
  short s; __builtin_memcpy(&s, &h, 2); return s;
}
__device__ __forceinline__ float b2f(short s){
  __hip_bfloat16 h; __builtin_memcpy(&h, &s, 2); return __bfloat162float(h);
}
__device__ __forceinline__ unsigned cvtpk(float a, float b){
  unsigned r;
  asm("v_cvt_pk_bf16_f32 %0, %1, %2" : "=v"(r) : "v"(a), "v"(b));
  return r;
}
__device__ __forceinline__ float wsum(float v){
  #pragma unroll
  for (int o = 32; o > 0; o >>= 1) v += __shfl_xor(v, o);
  return v;
}

// ---------------- fused prep: 4x weight transpose+cast + relpos cast + LN1 ----
__device__ __forceinline__ void wt_tile(const float* __restrict__ W,
    __hip_bfloat16* __restrict__ Wt, int K, int N, int tx, int ty,
    float (*t)[33], int tid){
  const int n0 = tx*32, k0 = ty*32;
  const int c = tid & 31, r0 = tid >> 5;
  #pragma unroll
  for (int i = 0; i < 4; ++i){
    int r = r0 + i*8;
    t[r][c] = W[(size_t)(k0 + r)*N + n0 + c];
  }
  __syncthreads();
  #pragma unroll
  for (int i = 0; i < 4; ++i){
    int r = r0 + i*8;
    Wt[(size_t)(n0 + r)*K + k0 + c] = __float2bfloat16(t[c][r]);
  }
}

__device__ __forceinline__ void ln_row(const float* __restrict__ xr,
    const float* __restrict__ g, const float* __restrict__ b,
    __hip_bfloat16* __restrict__ o, float* sm, int tid){
  float v0 = xr[tid], v1 = xr[tid+256], v2 = xr[tid+512];
  float s = wsum(v0+v1+v2);
  if ((tid & 63)==0) sm[tid>>6] = s;
  __syncthreads();
  float mean = (sm[0]+sm[1]+sm[2]+sm[3]) * (1.0f/CDIM);
  __syncthreads();
  float d0=v0-mean, d1=v1-mean, d2=v2-mean;
  float ss = wsum(d0*d0+d1*d1+d2*d2);
  if ((tid&63)==0) sm[tid>>6] = ss;
  __syncthreads();
  float rstd = rsqrtf((sm[0]+sm[1]+sm[2]+sm[3])*(1.0f/CDIM) + 1e-6f);
  o[tid]     = __float2bfloat16(d0*rstd*g[tid]     + b[tid]);
  o[tid+256] = __float2bfloat16(d1*rstd*g[tid+256] + b[tid+256]);
  o[tid+512] = __float2bfloat16(d2*rstd*g[tid+512] + b[tid+512]);
}

__global__ __launch_bounds__(256) void prep_kernel(
    const float* __restrict__ qkv_w, const float* __restrict__ proj_w,
    const float* __restrict__ m1w, const float* __restrict__ m2w,
    const float* __restrict__ rph, const float* __restrict__ rpw,
    const float* __restrict__ x, const float* __restrict__ ln1_g,
    const float* __restrict__ ln1_b,
    __hip_bfloat16* __restrict__ qkvT, __hip_bfloat16* __restrict__ projT,
    __hip_bfloat16* __restrict__ m1T, __hip_bfloat16* __restrict__ m2T,
    __hip_bfloat16* __restrict__ rphb, __hip_bfloat16* __restrict__ rpwb,
    __hip_bfloat16* __restrict__ yb){
  __shared__ float t[32][33];
  __shared__ float sm[4];
  int id = blockIdx.x, tid = threadIdx.x;
  if (id < 1728)      wt_tile(qkv_w, qkvT, 768, 2304, id%72, id/72, t, tid);
  else if (id < 2304){ id -= 1728; wt_tile(proj_w, projT, 768, 768, id%24, id/24, t, tid); }
  else if (id < 4608){ id -= 2304; wt_tile(m1w, m1T, 768, 3072, id%96, id/96, t, tid); }
  else if (id < 6912){ id -= 4608; wt_tile(m2w, m2T, 3072, 768, id%24, id/24, t, tid); }
  else if (id < 6936){
    int i = (id - 6912)*256 + tid;
    if (i < 95*64){ rphb[i] = __float2bfloat16(rph[i]); rpwb[i] = __float2bfloat16(rpw[i]); }
  } else {
    int row = id - 6936;
    ln_row(x + (size_t)row*CDIM, ln1_g, ln1_b, yb + (size_t)row*CDIM, sm, tid);
  }
}

// ------------- V transpose: qkvb[n][1536+h*64+d] -> Vtg[h][d][n] -------------
__global__ __launch_bounds__(256) void vt_kernel(const __hip_bfloat16* __restrict__ qkvb,
    __hip_bfloat16* __restrict__ Vtg){
  __shared__ __hip_bfloat16 t[32][33];
  const int n0 = blockIdx.x*32, d0 = blockIdx.y*32, h = blockIdx.z;
  const int c = threadIdx.x & 31, r0 = threadIdx.x >> 5;
  #pragma unroll
  for (int i = 0; i < 4; ++i){
    int r = r0 + i*8;
    t[r][c] = qkvb[(size_t)(n0+r)*NTOK + 1536 + h*64 + d0 + c];
  }
  __syncthreads();
  #pragma unroll
  for (int i = 0; i < 4; ++i){
    int r = r0 + i*8;
    Vtg[((size_t)h*64 + d0 + r)*NTOK + n0 + c] = t[c][r];
  }
}

// ------------- bf16 MFMA GEMM, 128x64 tile, 2-phase prefetch ------------------
// Compile-time KSTEPS (full unroll), bijective XCD swizzle with M-fastest
// logical order (B-panel reuse per XCD L2), setprio around MFMA cluster.
// PARTIAL=0: C=bf16(A@Bt^T + bias [gelu]); PARTIAL=1: f32 partial (no bias).
template<int KSTEPS, int ACT, int PARTIAL>
__global__ __launch_bounds__(256) void gemm_bf16(
    const __hip_bfloat16* __restrict__ A, const __hip_bfloat16* __restrict__ Bt,
    const float* __restrict__ bias, void* __restrict__ Cout,
    int M, int K, int N, int gm){
  __shared__ short As[2][128*32];
  __shared__ short Bs[2][64*32];
  const int tid = threadIdx.x;
  const int w = tid >> 6, lane = tid & 63;
  const int wr = w >> 1, wc = w & 1;

  // XCD-aware bijective swizzle (gridDim.x % 8 == 0 for all our launches):
  // blocks with the same (blockIdx.x % 8) land on the same XCD; give them a
  // contiguous run of logical ids, M-fastest, so B panels stay L2-resident.
  const int nwg = gridDim.x;
  const int wg = (blockIdx.x & 7) * (nwg >> 3) + (blockIdx.x >> 3);
  const int bm = (wg % gm) * 128, bn = (wg / gm) * 64;

  const int kbase = blockIdx.y * KSTEPS * 32;
  const int l15 = lane & 15, l4 = lane >> 4;
  f32x4 acc[4][2] = {};

  const int ra = wr*64 + l15;          // wave M-tile 64
  const int rb = wc*32 + l15;          // wave N-tile 32
  const int kswa = l4 ^ ((ra>>1)&3);
  const int kswb = l4 ^ ((rb>>1)&3);

  auto STAGE = [&](int buf, int k0){
    #pragma unroll
    for (int r = 0; r < 3; ++r){
      if (r < 2){
        int e = r*256 + tid;
        int row = e >> 2, s = e & 3, gs = s ^ ((row>>1)&3);
        GLOAD16(A + (size_t)(bm+row)*K + k0 + gs*8, (char*)As[buf] + ((r*256 + w*64)<<4));
      } else {
        int e = tid;
        int row = e >> 2, s = e & 3, gs = s ^ ((row>>1)&3);
        GLOAD16(Bt + (size_t)(bn+row)*K + k0 + gs*8, (char*)Bs[buf] + ((w*64)<<4));
      }
    }
  };

  STAGE(0, kbase);
  __syncthreads();
  #pragma unroll
  for (int t = 0; t < KSTEPS; ++t){
    const int cur = t & 1;
    if (t+1 < KSTEPS) STAGE(cur^1, kbase + (t+1)*32);
    bf16x8 af[4], bfr[2];
    #pragma unroll
    for (int m = 0; m < 4; ++m)
      af[m] = *(const bf16x8*)((const char*)As[cur] + (ra + m*16)*64 + kswa*16);
    #pragma unroll
    for (int n = 0; n < 2; ++n)
      bfr[n] = *(const bf16x8*)((const char*)Bs[cur] + (rb + n*16)*64 + kswb*16);
    __builtin_amdgcn_s_setprio(1);
    #pragma unroll
    for (int m = 0; m < 4; ++m)
      #pragma unroll
      for (int n = 0; n < 2; ++n)
        acc[m][n] = MFMA16(af[m], bfr[n], acc[m][n]);
    __builtin_amdgcn_s_setprio(0);
    __syncthreads();
  }

  const int crow = bm + wr*64 + l4*4;
  const int ccol = bn + wc*32 + l15;
  float* Cp = (float*)Cout + (size_t)blockIdx.y*M*N;
  #pragma unroll
  for (int m = 0; m < 4; ++m){
    #pragma unroll
    for (int n = 0; n < 2; ++n){
      #pragma unroll
      for (int r = 0; r < 4; ++r){
        int rr = crow + m*16 + r, cc = ccol + n*16;
        if (PARTIAL){
          Cp[(size_t)rr*N + cc] = acc[m][n][r];
        } else {
          float v = acc[m][n][r] + bias[cc];
          if (ACT == 1) v = 0.5f * v * (1.0f + erff(v * 0.70710678118654752f));
          ((__hip_bfloat16*)Cout)[(size_t)rr*N + cc] = __float2bfloat16(v);
        }
      }
    }
  }
}

// ------------- MFMA flash attention, KV-split x3, double-buffered staging ----
// grid (36, 12, 3): 64 queries/block (4 waves x 16q), part z does chunks [12z,12z+12)
__global__ __launch_bounds__(256) void attn_mfma(
    const __hip_bfloat16* __restrict__ qkvb,  // [2304][2304]
    const __hip_bfloat16* __restrict__ Vtg,   // [12][64][2304]
    const __hip_bfloat16* __restrict__ rphb,  // [95][64]
    const __hip_bfloat16* __restrict__ rpwb,  // [95][64]
    __hip_bfloat16* __restrict__ Opart,       // [3][2304][768] unnormalized
    float2* __restrict__ ml){                 // [3][12][2304]
  __shared__ short KVbuf[4][64*64];  // [b]=Ks buf b, [2+b]=Vs buf b (dbuf)
  __shared__ short rlh_l[4][16][16]; // rel-h window for this part (bf16)
  __shared__ unsigned p_lds[4][16][32]; // P tile per wave, swizzled

  short* rlt_sh = &KVbuf[0][0];      // one-time overlay [4][16][66] bf16 (8448B)

  const int tid = threadIdx.x;
  const int w = tid >> 6, lane = tid & 63;
  const int head = blockIdx.y;
  const int part = blockIdx.z;
  const int n0 = blockIdx.x * 64;
  const int qbase = n0 + w*16;
  const int hq = qbase / 48;
  const int wq0 = qbase % 48;
  const int q = lane & 15, g = lane >> 4;

  // Q fragments (B-operand layout: col=q=lane&15, k=g*8+j), scaled by 1/8
  bf16x8 qf[2];
  {
    const __hip_bfloat16* qp = qkvb + (size_t)(qbase + q)*NTOK + head*64 + g*8;
    #pragma unroll
    for (int ks = 0; ks < 2; ++ks){
      bf16x8 t = *(const bf16x8*)(qp + 32*ks);
      #pragma unroll
      for (int j = 0; j < 8; ++j) t[j] = f2b(b2f(t[j]) * 0.125f);
      qf[ks] = t;
    }
  }

  // rel-h for the 16 hk rows this part touches (hk = part*16 + g*4 + r)
  {
    int grow = hq - (part*16 + q) + 47;
    f32x4 c = {};
    #pragma unroll
    for (int ks = 0; ks < 2; ++ks){
      bf16x8 a = *(const bf16x8*)(rphb + grow*64 + g*8 + 32*ks);
      c = MFMA16(a, qf[ks], c);
    }
    #pragma unroll
    for (int r = 0; r < 4; ++r) rlh_l[w][q][g*4 + r] = f2b(c[r] * 8.0f);
  }
  // rel-w table T[u][q] = q . Rw[wq0+62-u]  (u = wk - q + 15), one-time overlay
  #pragma unroll
  for (int f = 0; f < 4; ++f){
    int grow = wq0 + 62 - (f*16 + q);
    if (grow < 0) grow = 0;
    f32x4 c = {};
    #pragma unroll
    for (int ks = 0; ks < 2; ++ks){
      bf16x8 a = *(const bf16x8*)(rpwb + grow*64 + g*8 + 32*ks);
      c = MFMA16(a, qf[ks], c);
    }
    #pragma unroll
    for (int r = 0; r < 4; ++r)
      rlt_sh[w*1056 + q*66 + f*16 + g*4 + r] = f2b(c[r] * 8.0f);
  }
  // hoist the 12 rel-w values this lane needs into registers:
  // u(r,j) = (g*4+r) + 16*j - q + 15, j = (4*ci+kf)%3 selector in main loop
  float rlt_reg[4][3];
  #pragma unroll
  for (int r = 0; r < 4; ++r)
    #pragma unroll
    for (int j = 0; j < 3; ++j)
      rlt_reg[r][j] = b2f(rlt_sh[w*1056 + q*66 + (g*4+r) + 16*j - q + 15]);

  __syncthreads();   // all waves done with the rlt overlay before staging begins

  float m_run = -1e30f, l_run = 0.f;
  f32x4 oacc[4] = {};   // lane: O[qrow=g*4+r][d=df*16+q]

  const __hip_bfloat16* kgbase = qkvb + 768 + head*64;
  const __hip_bfloat16* vgbase = Vtg + (size_t)head*64*NTOK;
  char* prow = (char*)&p_lds[w][q][0];
  const int qs = q & 7;

  auto STAGE_KV = [&](int buf, int ch){
    #pragma unroll
    for (int i = 0; i < 2; ++i){
      int e = i*256 + tid;
      int row = e >> 3, s = e & 7;
      int e0 = i*256 + w*64;
      GLOAD16(kgbase + (size_t)(ch*64 + row)*NTOK + (s ^ (row & 7))*8,
              (char*)KVbuf[buf] + e0*16);
      GLOAD16(vgbase + (size_t)row*NTOK + ch*64 + (s ^ (row & 7))*8,
              (char*)KVbuf[2+buf] + e0*16);
    }
  };

  STAGE_KV(0, part*12);          // prologue
  int cur = 0;
  #pragma unroll
  for (int ci = 0; ci < 12; ++ci){
    __syncthreads();             // drains cur's loads; separates buffer reuse
    if (ci+1 < 12) STAGE_KV(cur^1, part*12 + ci + 1);  // overlap next with compute
    const short* Ks = KVbuf[cur];
    const short* Vs = KVbuf[2+cur];

    // St[key][q] = (Q*scale) . K   (key = kf*16 + q as A-row)
    f32x4 st[4];
    #pragma unroll
    for (int kf = 0; kf < 4; ++kf){
      int key = kf*16 + q;
      f32x4 c = {};
      #pragma unroll
      for (int ks = 0; ks < 2; ++ks){
        int slot = (4*ks + g) ^ qs;
        bf16x8 kf8 = *(const bf16x8*)((const char*)Ks + key*128 + slot*16);
        c = MFMA16(kf8, qf[ks], c);
      }
      st[kf] = c;
    }

    // add rel bias: per-kf constant hk, register rel-w (selector compile-time)
    float sv[4][4];
    #pragma unroll
    for (int kf = 0; kf < 4; ++kf){
      const int m = (4*ci + kf) % 3;
      const int hloc = (4*ci + kf - m) / 3;
      float rh = b2f(rlh_l[w][q][hloc]);
      #pragma unroll
      for (int r = 0; r < 4; ++r)
        sv[kf][r] = st[kf][r] + rh + rlt_reg[r][m];
    }

    // online softmax over the 4-lane q-group, defer-max THR=8
    float cmax = -1e30f;
    #pragma unroll
    for (int kf = 0; kf < 4; ++kf)
      #pragma unroll
      for (int r = 0; r < 4; ++r) cmax = fmaxf(cmax, sv[kf][r]);
    cmax = fmaxf(cmax, __shfl_xor(cmax, 16));
    cmax = fmaxf(cmax, __shfl_xor(cmax, 32));
    float fs = 1.0f;
    if (__any(cmax > m_run + 8.0f)){
      float nm = fmaxf(m_run, cmax);
      fs = __expf(m_run - nm);
      m_run = nm;
      float fr[4];
      #pragma unroll
      for (int r = 0; r < 4; ++r) fr[r] = __shfl(fs, g*4 + r);
      #pragma unroll
      for (int df = 0; df < 4; ++df)
        #pragma unroll
        for (int r = 0; r < 4; ++r) oacc[df][r] *= fr[r];
    }
    float p[4][4]; float lsum = 0.f;
    #pragma unroll
    for (int kf = 0; kf < 4; ++kf)
      #pragma unroll
      for (int r = 0; r < 4; ++r){ p[kf][r] = __expf(sv[kf][r] - m_run); lsum += p[kf][r]; }
    lsum += __shfl_xor(lsum, 16);
    lsum += __shfl_xor(lsum, 32);
    l_run = l_run * fs + lsum;

    // P -> bf16 -> swizzled LDS (wave-private), then PV via b128 reads
    #pragma unroll
    for (int kf = 0; kf < 4; ++kf){
      unsigned lo = cvtpk(p[kf][0], p[kf][1]);
      unsigned hi = cvtpk(p[kf][2], p[kf][3]);
      *(uint2*)(prow + (((2*kf + (g>>1)) ^ qs) << 4) + ((g&1) << 3)) = make_uint2(lo, hi);
    }
    #pragma unroll
    for (int ks = 0; ks < 2; ++ks){
      bf16x8 pa = *(const bf16x8*)(prow + (((4*ks + g) ^ qs) << 4));
      #pragma unroll
      for (int df = 0; df < 4; ++df){
        int d = df*16 + q;
        int slot = (4*ks + g) ^ qs;
        bf16x8 vf8 = *(const bf16x8*)((const char*)Vs + d*128 + slot*16);
        oacc[df] = MFMA16(pa, vf8, oacc[df]);
      }
    }
    cur ^= 1;
  }

  // write unnormalized partial O + (m,l) per q-row
  __hip_bfloat16* op = Opart + (size_t)part*NTOK*CDIM;
  #pragma unroll
  for (int df = 0; df < 4; ++df)
    #pragma unroll
    for (int r = 0; r < 4; ++r)
      op[(size_t)(qbase + g*4 + r)*CDIM + head*64 + df*16 + q] =
          __float2bfloat16(oacc[df][r]);
  if (g == 0)
    ml[(size_t)part*12*NTOK + head*NTOK + qbase + q] = make_float2(m_run, l_run);
}

// ------------- merge the 3 KV-split partials -------------
__global__ __launch_bounds__(256) void merge_attn(
    const __hip_bfloat16* __restrict__ Opart, const float2* __restrict__ ml,
    __hip_bfloat16* __restrict__ attb){
  const int n = blockIdx.x, tid = threadIdx.x;
  #pragma unroll
  for (int j = 0; j < 3; ++j){
    int c = tid + j*256;
    int h = c >> 6;
    float2 a = ml[h*NTOK + n];
    float2 b = ml[12*NTOK + h*NTOK + n];
    float2 d = ml[2*12*NTOK + h*NTOK + n];
    float M = fmaxf(a.x, fmaxf(b.x, d.x));
    float e0 = __expf(a.x - M), e1 = __expf(b.x - M), e2 = __expf(d.x - M);
    float L = a.y*e0 + b.y*e1 + d.y*e2;
    float o0 = __bfloat162float(Opart[(size_t)n*CDIM + c]);
    float o1 = __bfloat162float(Opart[(size_t)NTOK*CDIM + n*CDIM + c]);
    float o2 = __bfloat162float(Opart[(size_t)2*NTOK*CDIM + n*CDIM + c]);
    attb[(size_t)n*CDIM + c] = __float2bfloat16((o0*e0 + o1*e1 + o2*e2) / L);
  }
}

// ------------- proj split-K(2) merge + residual + LN2 fused -------------
__global__ __launch_bounds__(256) void merge_proj_ln(
    const float* __restrict__ x, const float* __restrict__ Cp,
    const float* __restrict__ pb,
    const float* __restrict__ g2, const float* __restrict__ b2,
    __hip_bfloat16* __restrict__ x1b, __hip_bfloat16* __restrict__ yb){
  __shared__ float sm[4];
  const int row = blockIdx.x, tid = threadIdx.x;
  float v[3];
  #pragma unroll
  for (int j = 0; j < 3; ++j){
    int c = tid + j*256;
    size_t o = (size_t)row*CDIM + c;
    float s = x[o] + pb[c];
    s += Cp[o] + Cp[(size_t)NTOK*CDIM + o];
    v[j] = s;
    x1b[o] = __float2bfloat16(s);
  }
  float s = wsum(v[0]+v[1]+v[2]);
  if ((tid & 63)==0) sm[tid>>6] = s;
  __syncthreads();
  float mean = (sm[0]+sm[1]+sm[2]+sm[3]) * (1.0f/CDIM);
  __syncthreads();
  float d0=v[0]-mean, d1=v[1]-mean, d2=v[2]-mean;
  float ss = wsum(d0*d0+d1*d1+d2*d2);
  if ((tid&63)==0) sm[tid>>6] = ss;
  __syncthreads();
  float rstd = rsqrtf((sm[0]+sm[1]+sm[2]+sm[3])*(1.0f/CDIM) + 1e-6f);
  __hip_bfloat16* o = yb + (size_t)row*CDIM;
  o[tid]     = __float2bfloat16(d0*rstd*g2[tid]     + b2[tid]);
  o[tid+256] = __float2bfloat16(d1*rstd*g2[tid+256] + b2[tid+256]);
  o[tid+512] = __float2bfloat16(d2*rstd*g2[tid+512] + b2[tid+512]);
}

// ------------- mlp2 split-K(3) merge + residual -> f32 out -------------
__global__ __launch_bounds__(256) void merge_mlp2(
    const __hip_bfloat16* __restrict__ x1b, const float* __restrict__ Cp,
    const float* __restrict__ bias, float* __restrict__ out){
  const int row = blockIdx.x, tid = threadIdx.x;
  #pragma unroll
  for (int j = 0; j < 3; ++j){
    int c = tid + j*256;
    size_t o = (size_t)row*CDIM + c;
    float s = __bfloat162float(x1b[o]) + bias[c];
    s += Cp[o] + Cp[(size_t)NTOK*CDIM + o] + Cp[(size_t)2*NTOK*CDIM + o];
    out[o] = s;
  }
}

extern "C" void kernel_launch(void* const* d_in, const int* in_sizes, int n_in,
                              void* d_out, int out_size, void* d_ws, size_t ws_size,
                              hipStream_t stream) {
  const float* x      = (const float*)d_in[0];
  const float* ln1_g  = (const float*)d_in[1];
  const float* ln1_b  = (const float*)d_in[2];
  const float* qkv_w  = (const float*)d_in[3];
  const float* qkv_b  = (const float*)d_in[4];
  const float* rph    = (const float*)d_in[5];
  const float* rpw    = (const float*)d_in[6];
  const float* proj_w = (const float*)d_in[7];
  const float* proj_b = (const float*)d_in[8];
  const float* ln2_g  = (const float*)d_in[9];
  const float* ln2_b  = (const float*)d_in[10];
  const float* mlp_w1 = (const float*)d_in[11];
  const float* mlp_b1 = (const float*)d_in[12];
  const float* mlp_w2 = (const float*)d_in[13];
  const float* mlp_b2 = (const float*)d_in[14];

  char* ws = (char*)d_ws;
  // layout (bytes), lifetime-checked:
  __hip_bfloat16* x1b   = (__hip_bfloat16*)(ws);              // [0, 3.54M)
  __hip_bfloat16* m2T   = (__hip_bfloat16*)(ws + 3538944);    // [3.54M, 8.26M)
  __hip_bfloat16* hb    = (__hip_bfloat16*)(ws + 8257536);    // [8.26M, 22.41M) (mlp1 out)
  __hip_bfloat16* qkvb  = (__hip_bfloat16*)(ws + 8257536);    // [8.26M, 18.87M) dead after attn
  __hip_bfloat16* Opart = (__hip_bfloat16*)(ws + 18874368);   // [18.87M, 29.49M)
  float*          Cpp   = (float*)         (ws + 8257536);    // proj partials x2 [8.26M, 22.41M)
  float*          Cpm   = (float*)         (ws + 22413312);   // mlp2 partials x3 [22.41M, 43.65M)
  float2*         mlbuf = (float2*)        (ws + 29491200);   // [29.49M, 30.15M)
  __hip_bfloat16* Vtg   = (__hip_bfloat16*)(ws + 30154752);   // [30.15M, 33.69M)
  __hip_bfloat16* qkvT  = (__hip_bfloat16*)(ws + 33693696);   // [33.69M, 37.23M)
  __hip_bfloat16* attb  = (__hip_bfloat16*)(ws + 33693696);   // alias, after qkv gemm
  __hip_bfloat16* projT = (__hip_bfloat16*)(ws + 37232640);   // [37.23M, 38.41M)
  __hip_bfloat16* m1T   = (__hip_bfloat16*)(ws + 38412288);   // [38.41M, 43.13M)
  __hip_bfloat16* rphb  = (__hip_bfloat16*)(ws + 43646976);
  __hip_bfloat16* rpwb  = (__hip_bfloat16*)(ws + 43659136);
  __hip_bfloat16* yb    = (__hip_bfloat16*)(ws + 43671296);   // [43.67M, 47.21M) ln out

  // prep: weight transposes + relpos cast + LN1 (ids 6936..9239)
  prep_kernel<<<9240, 256, 0, stream>>>(qkv_w, proj_w, mlp_w1, mlp_w2, rph, rpw,
                                        x, ln1_g, ln1_b,
                                        qkvT, projT, m1T, m2T, rphb, rpwb, yb);

  // qkv = xn @ qkv_w + b   (2304 x 768 x 2304), 648 blocks, K=24 steps
  gemm_bf16<24,0,0><<<dim3(648), 256, 0, stream>>>(
      yb, qkvT, qkv_b, qkvb, NTOK, 768, 2304, 18);

  vt_kernel<<<dim3(72, 2, 12), 256, 0, stream>>>(qkvb, Vtg);
  attn_mfma<<<dim3(36, 12, 3), 256, 0, stream>>>(qkvb, Vtg, rphb, rpwb, Opart, mlbuf);
  merge_attn<<<NTOK, 256, 0, stream>>>(Opart, mlbuf, attb);

  // proj partials (2304 x 768 x 768), split-K=2 -> 432 blocks, 12 steps
  gemm_bf16<12,0,1><<<dim3(216, 2), 256, 0, stream>>>(
      attb, projT, nullptr, Cpp, NTOK, 768, 768, 18);
  merge_proj_ln<<<NTOK, 256, 0, stream>>>(x, Cpp, proj_b, ln2_g, ln2_b, x1b, yb);

  // h = gelu(y @ mlp_w1 + b)   (2304 x 768 x 3072) -> 864 blocks, 24 steps
  gemm_bf16<24,1,0><<<dim3(864), 256, 0, stream>>>(
      yb, m1T, mlp_b1, hb, NTOK, 768, 3072, 18);

  // mlp2 partials (2304 x 3072 x 768), split-K=3 -> 648 blocks, 32 steps
  gemm_bf16<32,0,1><<<dim3(216, 3), 256, 0, stream>>>(
      hb, m2T, nullptr, Cpm, NTOK, 3072, 768, 18);
  merge_mlp2<<<NTOK, 256, 0, stream>>>(x1b, Cpm, mlp_b2, (float*)d_out);
}